// Round 22
// baseline (1593.049 us; speedup 1.0000x reference)
//
#include <hip/hip_runtime.h>
#include <stdint.h>

#define B_    2
#define SEQ   2048
#define HID   2048
#define NK_   16
#define NV_   32
#define DK_   128
#define DV_   128
#define NQKVZ 12288
#define CONVD 8192
#define MTOT  (B_*SEQ)   // 4096
#define CCH   16         // recurrence sub-chunk length
#define T0TOK 1216       // partition 0 length (76 chunks, single chain)
#define HTOK2 832        // partition 1 length (52 chunks, merged dual chain)
#define CT    8          // conv rolling tile
#define RLDSZ 110592     // recurrence dynamic LDS

typedef unsigned short ushort_t;
typedef __bf16 bf16x8 __attribute__((ext_vector_type(8)));
typedef float  f32x4  __attribute__((ext_vector_type(4)));
typedef unsigned short us4 __attribute__((ext_vector_type(4)));

__device__ __forceinline__ ushort_t f2bf(float f){
  union { float f; unsigned u; } v; v.f = f;
  unsigned r = v.u + 0x7FFFu + ((v.u >> 16) & 1u);
  return (ushort_t)(r >> 16);
}
__device__ __forceinline__ float bf2f(ushort_t u){
  union { unsigned u; float f; } v; v.u = ((unsigned)u) << 16; return v.f;
}
__device__ __forceinline__ float sigmoidf_(float x){ return 1.f/(1.f+__expf(-x)); }
__device__ __forceinline__ float siluf_(float x){ return x*sigmoidf_(x); }

// ---------------- cast x -> bf16 ----------------
__global__ void cast_x_kernel(const float* __restrict__ x, ushort_t* __restrict__ xb, int n4){
  int i = blockIdx.x*256 + threadIdx.x;
  if (i >= n4) return;
  float4 v = ((const float4*)x)[i];
  us4 o; o[0]=f2bf(v.x); o[1]=f2bf(v.y); o[2]=f2bf(v.z); o[3]=f2bf(v.w);
  ((us4*)xb)[i] = o;
}

// ---------------- transpose + cast W[K][N] -> Wt[N][K] bf16 ----------------
__global__ __launch_bounds__(256) void transpose_cast(const float* __restrict__ W, ushort_t* __restrict__ Wt,
                                                      int K, int N){
  __shared__ float tile[64][65];
  int n0 = blockIdx.x*64, k0 = blockIdx.y*64;
  int tx = threadIdx.x & 63, ty = threadIdx.x >> 6;
  #pragma unroll
  for (int i=0;i<16;i++){
    int kr = ty + i*4;
    tile[kr][tx] = W[(size_t)(k0+kr)*N + n0+tx];
  }
  __syncthreads();
  #pragma unroll
  for (int i=0;i<16;i++){
    int nr = ty + i*4;
    Wt[(size_t)(n0+nr)*K + k0+tx] = f2bf(tile[tx][nr]);
  }
}

// ---------------- big-tile GEMM: 256x256, BK=32, 3-deep pipeline, counted vmcnt ----------------
template<int OUTBF>
__global__ __launch_bounds__(512, 2) void gemm_big(const ushort_t* __restrict__ A, const ushort_t* __restrict__ Bt,
                                                   void* __restrict__ Cv, int M, int N, int K){
  extern __shared__ ushort_t dynlds[];
  ushort_t* SA = dynlds;
  ushort_t* SB = dynlds + 3*8192;
  const int t = threadIdx.x;
  const int lane = t & 63, w = t >> 6;
  const int wm = w >> 2, wn = w & 3;
  const int lr = lane & 15, hk = lane >> 4;
  const int gx = gridDim.x;
  const int nwg = gx * gridDim.y;
  const int flat = blockIdx.y*gx + blockIdx.x;
  const int cpx = nwg >> 3;
  const int swzb = (flat & 7)*cpx + (flat >> 3);
  const int m0 = (swzb / gx) * 256, n0 = (swzb % gx) * 256;

  int srow[2], scol[2];
  #pragma unroll
  for (int q=0;q<2;q++){
    int p  = (w*2+q)*1024 + lane*16;
    int lg = p ^ (((p>>9)&1)<<5);
    srow[q] = lg >> 6;
    scol[q] = (lg & 63) >> 1;
  }
  int phA[8], phB[4];
  #pragma unroll
  for (int mi=0;mi<8;mi++){
    int lg = (wm*128 + mi*16 + lr)*64 + hk*16;
    phA[mi] = lg ^ (((lg>>9)&1)<<5);
  }
  #pragma unroll
  for (int ni=0;ni<4;ni++){
    int lg = (wn*64 + ni*16 + lr)*64 + hk*16;
    phB[ni] = lg ^ (((lg>>9)&1)<<5);
  }

  auto stage = [&](int j, int bufb){
    #pragma unroll
    for (int q=0;q<2;q++)
      __builtin_amdgcn_global_load_lds(
        (const __attribute__((address_space(1))) void*)(A + (size_t)(m0+srow[q])*K + j*32 + scol[q]),
        (__attribute__((address_space(3))) void*)(SA + bufb*8192 + (w*2+q)*512), 16, 0, 0);
    #pragma unroll
    for (int q=0;q<2;q++)
      __builtin_amdgcn_global_load_lds(
        (const __attribute__((address_space(1))) void*)(Bt + (size_t)(n0+srow[q])*K + j*32 + scol[q]),
        (__attribute__((address_space(3))) void*)(SB + bufb*8192 + (w*2+q)*512), 16, 0, 0);
  };

  f32x4 acc[8][4];
  #pragma unroll
  for (int mi=0;mi<8;mi++)
    #pragma unroll
    for (int ni=0;ni<4;ni++) acc[mi][ni] = (f32x4){0.f,0.f,0.f,0.f};

  const int NT = K >> 5;
  stage(0, 0);
  stage(1, 1);
  asm volatile("s_waitcnt vmcnt(4)" ::: "memory");
  __builtin_amdgcn_s_barrier();
  __builtin_amdgcn_sched_barrier(0);

  int cur = 0;
  for (int j = 0; j < NT; ++j){
    int nb = cur + 2; if (nb >= 3) nb -= 3;
    if (j + 2 < NT) stage(j+2, nb);
    const char* bA = (const char*)(SA + cur*8192);
    const char* bB = (const char*)(SB + cur*8192);
    bf16x8 af[8], bfv[4];
    #pragma unroll
    for (int mi=0;mi<8;mi++) af[mi]  = *(const bf16x8*)(bA + phA[mi]);
    #pragma unroll
    for (int ni=0;ni<4;ni++) bfv[ni] = *(const bf16x8*)(bB + phB[ni]);
    #pragma unroll
    for (int mi=0;mi<8;mi++)
      #pragma unroll
      for (int ni=0;ni<4;ni++)
        acc[mi][ni] = __builtin_amdgcn_mfma_f32_16x16x32_bf16(af[mi], bfv[ni], acc[mi][ni], 0, 0, 0);
    if (j + 2 < NT){
      asm volatile("s_waitcnt vmcnt(4)" ::: "memory");
      __builtin_amdgcn_s_barrier();
      __builtin_amdgcn_sched_barrier(0);
    } else if (j + 1 < NT){
      asm volatile("s_waitcnt vmcnt(0)" ::: "memory");
      __builtin_amdgcn_s_barrier();
      __builtin_amdgcn_sched_barrier(0);
    }
    cur = cur + 1; if (cur >= 3) cur -= 3;
  }

  #pragma unroll
  for (int mi=0;mi<8;mi++)
    #pragma unroll
    for (int ni=0;ni<4;ni++)
      #pragma unroll
      for (int r=0;r<4;r++){
        int m = m0 + wm*128 + mi*16 + hk*4 + r;
        int n = n0 + wn*64  + ni*16 + lr;
        if (OUTBF) ((ushort_t*)Cv)[(size_t)m*N + n] = f2bf(acc[mi][ni][r]);
        else       ((float*)Cv)[(size_t)m*N + n]    = acc[mi][ni][r];
      }
}

// ---------------- big-tile GEMM variant: 256M x 128N ----------------
template<int OUTBF>
__global__ __launch_bounds__(512, 2) void gemm_big2(const ushort_t* __restrict__ A, const ushort_t* __restrict__ Bt,
                                                    void* __restrict__ Cv, int M, int N, int K){
  extern __shared__ ushort_t dynlds[];
  ushort_t* SA = dynlds;
  ushort_t* SB = dynlds + 3*8192;
  const int t = threadIdx.x;
  const int lane = t & 63, w = t >> 6;
  const int wm = w >> 1, wn = w & 1;
  const int lr = lane & 15, hk = lane >> 4;
  const int gx = gridDim.x;
  const int nwg = gx * gridDim.y;
  const int flat = blockIdx.y*gx + blockIdx.x;
  const int cpx = nwg >> 3;
  const int swzb = (flat & 7)*cpx + (flat >> 3);
  const int m0 = (swzb / gx) * 256, n0 = (swzb % gx) * 128;

  int srA[2], scA[2];
  #pragma unroll
  for (int q=0;q<2;q++){
    int p  = (w*2+q)*1024 + lane*16;
    int lg = p ^ (((p>>9)&1)<<5);
    srA[q] = lg >> 6;
    scA[q] = (lg & 63) >> 1;
  }
  int srB, scB;
  {
    int p  = w*1024 + lane*16;
    int lg = p ^ (((p>>9)&1)<<5);
    srB = lg >> 6;
    scB = (lg & 63) >> 1;
  }
  int phA[4], phB[4];
  #pragma unroll
  for (int mi=0;mi<4;mi++){
    int lg = (wm*64 + mi*16 + lr)*64 + hk*16;
    phA[mi] = lg ^ (((lg>>9)&1)<<5);
  }
  #pragma unroll
  for (int ni=0;ni<4;ni++){
    int lg = (wn*64 + ni*16 + lr)*64 + hk*16;
    phB[ni] = lg ^ (((lg>>9)&1)<<5);
  }

  auto stage = [&](int j, int bufb){
    #pragma unroll
    for (int q=0;q<2;q++)
      __builtin_amdgcn_global_load_lds(
        (const __attribute__((address_space(1))) void*)(A + (size_t)(m0+srA[q])*K + j*32 + scA[q]),
        (__attribute__((address_space(3))) void*)(SA + bufb*8192 + (w*2+q)*512), 16, 0, 0);
    __builtin_amdgcn_global_load_lds(
        (const __attribute__((address_space(1))) void*)(Bt + (size_t)(n0+srB)*K + j*32 + scB),
        (__attribute__((address_space(3))) void*)(SB + bufb*4096 + w*512), 16, 0, 0);
  };

  f32x4 acc[4][4];
  #pragma unroll
  for (int mi=0;mi<4;mi++)
    #pragma unroll
    for (int ni=0;ni<4;ni++) acc[mi][ni] = (f32x4){0.f,0.f,0.f,0.f};

  const int NT = K >> 5;
  stage(0, 0);
  stage(1, 1);
  asm volatile("s_waitcnt vmcnt(3)" ::: "memory");
  __builtin_amdgcn_s_barrier();
  __builtin_amdgcn_sched_barrier(0);

  int cur = 0;
  for (int j = 0; j < NT; ++j){
    int nb = cur + 2; if (nb >= 3) nb -= 3;
    if (j + 2 < NT) stage(j+2, nb);
    const char* bA = (const char*)(SA + cur*8192);
    const char* bB = (const char*)(SB + cur*4096);
    bf16x8 af[4], bfv[4];
    #pragma unroll
    for (int mi=0;mi<4;mi++) af[mi]  = *(const bf16x8*)(bA + phA[mi]);
    #pragma unroll
    for (int ni=0;ni<4;ni++) bfv[ni] = *(const bf16x8*)(bB + phB[ni]);
    #pragma unroll
    for (int mi=0;mi<4;mi++)
      #pragma unroll
      for (int ni=0;ni<4;ni++)
        acc[mi][ni] = __builtin_amdgcn_mfma_f32_16x16x32_bf16(af[mi], bfv[ni], acc[mi][ni], 0, 0, 0);
    if (j + 2 < NT){
      asm volatile("s_waitcnt vmcnt(3)" ::: "memory");
      __builtin_amdgcn_s_barrier();
      __builtin_amdgcn_sched_barrier(0);
    } else if (j + 1 < NT){
      asm volatile("s_waitcnt vmcnt(0)" ::: "memory");
      __builtin_amdgcn_s_barrier();
      __builtin_amdgcn_sched_barrier(0);
    }
    cur = cur + 1; if (cur >= 3) cur -= 3;
  }

  #pragma unroll
  for (int mi=0;mi<4;mi++)
    #pragma unroll
    for (int ni=0;ni<4;ni++)
      #pragma unroll
      for (int r=0;r<4;r++){
        int m = m0 + wm*64 + mi*16 + hk*4 + r;
        int n = n0 + wn*64 + ni*16 + lr;
        if (OUTBF) ((ushort_t*)Cv)[(size_t)m*N + n] = f2bf(acc[mi][ni][r]);
        else       ((float*)Cv)[(size_t)m*N + n]    = acc[mi][ni][r];
      }
}

// ---------------- ba = x @ W_ba (fp32, N=64) ----------------
__global__ __launch_bounds__(256) void gemm_ba(const float* __restrict__ x, const float* __restrict__ Wba,
                                               float* __restrict__ ba){
  int lane = threadIdx.x & 63;
  int wid  = threadIdx.x >> 6;
  int row  = blockIdx.x*4 + wid;
  const float* xr = x + (size_t)row*HID;
  float acc = 0.f;
  for (int k=0;k<HID;k+=4){
    float4 xv = *(const float4*)&xr[k];
    acc += xv.x * Wba[(size_t)(k+0)*64 + lane];
    acc += xv.y * Wba[(size_t)(k+1)*64 + lane];
    acc += xv.z * Wba[(size_t)(k+2)*64 + lane];
    acc += xv.w * Wba[(size_t)(k+3)*64 + lane];
  }
  ba[(size_t)row*64 + lane] = acc;
}

// ---------------- conv(k=4) + SiLU + q/k RMS-norm (rolling window) ----------------
__global__ __launch_bounds__(256) void conv_norm_kernel(const ushort_t* __restrict__ qkvz, const float* __restrict__ conv_w,
                                                        ushort_t* __restrict__ qkv){
  const int blk = blockIdx.x;
  const int bt0 = (blk >> 4) * CT;
  const int ts0 = bt0 & (SEQ-1);
  const int gi = (blk & 15)*4 + (threadIdx.x >> 6);
  const int e2 = threadIdx.x & 63;
  const int dk = 2*e2;
  int col;
  if (gi < 16)       col = gi*768 + dk;
  else if (gi < 32)  col = (gi-16)*768 + 128 + dk;
  else { int nv = gi-32; col = (nv>>1)*768 + 256 + (nv&1)*128 + dk; }
  const int c = gi*128 + dk;
  const float4 w0 = *(const float4*)&conv_w[(size_t)c*4];
  const float4 w1 = *(const float4*)&conv_w[(size_t)(c+1)*4];
  ushort2 h0 = (ts0>=1) ? *(const ushort2*)&qkvz[(size_t)(bt0-3)*NQKVZ + col] : make_ushort2(0,0);
  ushort2 h1 = (ts0>=1) ? *(const ushort2*)&qkvz[(size_t)(bt0-2)*NQKVZ + col] : make_ushort2(0,0);
  ushort2 h2 = (ts0>=1) ? *(const ushort2*)&qkvz[(size_t)(bt0-1)*NQKVZ + col] : make_ushort2(0,0);
  const float scale = (gi < 16) ? (1.f/128.f) : 0.08838834764831845f;
  #pragma unroll
  for (int tt=0; tt<CT; ++tt){
    const int bt = bt0 + tt;
    ushort2 h3 = *(const ushort2*)&qkvz[(size_t)bt*NQKVZ + col];
    float y0 = siluf_(bf2f(h0.x)*w0.x + bf2f(h1.x)*w0.y + bf2f(h2.x)*w0.z + bf2f(h3.x)*w0.w);
    float y1 = siluf_(bf2f(h0.y)*w1.x + bf2f(h1.y)*w1.y + bf2f(h2.y)*w1.z + bf2f(h3.y)*w1.w);
    float o0 = y0, o1 = y1;
    if (gi < 32){
      float ss = y0*y0 + y1*y1;
      #pragma unroll
      for (int o=1;o<64;o<<=1) ss += __shfl_xor(ss, o);
      float rs = rsqrtf(ss*(1.f/128.f) + 1e-6f);
      o0 = y0*rs*scale; o1 = y1*rs*scale;
    }
    ushort2 ov; ov.x = f2bf(o0); ov.y = f2bf(o1);
    *(ushort2*)&qkv[(size_t)bt*CONVD + gi*128 + dk] = ov;
    h0 = h1; h1 = h2; h2 = h3;
  }
}

// ---------------- {g, beta} as float2 ----------------
__global__ void gbeta_kernel(const float* __restrict__ ba, const float* __restrict__ A_log,
                             const float* __restrict__ dt_bias, float2* __restrict__ egb){
  int idx = blockIdx.x*256 + threadIdx.x;
  if (idx >= MTOT*NV_) return;
  int nv = idx & 31;
  int bt = idx >> 5;
  int nk = nv >> 1, r = nv & 1;
  float bg = ba[(size_t)bt*64 + nk*4 + r];
  float ag = ba[(size_t)bt*64 + nk*4 + 2 + r];
  float ad = ag + dt_bias[nv];
  float sp = fmaxf(ad, 0.f) + log1pf(__expf(-fabsf(ad)));
  float g  = -__expf(A_log[nv]) * sp;
  egb[idx] = make_float2(g, sigmoidf_(bg));
}

// ---------------- chunked gated delta-rule, seq-parallel P=2, MERGED 2nd blocks, 2-barrier schedule ----------------
// Substitution distributed per wave; frag select is VALUE-select on hk (all array indices compile-time).
__global__ __launch_bounds__(512) void recurrence_chunked(const ushort_t* __restrict__ qkv,
                                                          const float2* __restrict__ egb,
                                                          float* __restrict__ outc,
                                                          ushort_t* __restrict__ oaug,
                                                          ushort_t* __restrict__ Sfin,
                                                          int pmode){
  extern __shared__ char rlds[];
  ushort_t* Kl  = (ushort_t*)(rlds + 0);       // 16*136
  ushort_t* S0h = (ushort_t*)(rlds + 4352);    // 64*136
  ushort_t* S0l = (ushort_t*)(rlds + 21760);
  ushort_t* T0h = (ushort_t*)(rlds + 39168);   // aug state
  ushort_t* T0l = (ushort_t*)(rlds + 56576);
  ushort_t* KT  = (ushort_t*)(rlds + 73984);   // 128*40
  ushort_t* Wl  = (ushort_t*)(rlds + 94464);   // 16*40
  float*    Al  = (float*)   (rlds + 95744);   // 16*20
  float*    Ul  = (float*)   (rlds + 97024);   // 128*20 (rows 0-63 real, 64-127 aug)
  float*    clB = (float*)   (rlds + 107264);  // [2][16]
  float*    blB = clB + 32;
  float*    eclB= clB + 64;
  float*    kslB= clB + 96;
  float*    c15B= clB + 128;                   // [2]

  const int bi = blockIdx.x;
  int hb, tokbase, ntok;
  bool ismrg = false, wsf = false;
  if (pmode == 0){ hb = bi; tokbase = 0; ntok = SEQ; }
  else {
    if (bi < 128){ hb = bi; tokbase = 0; ntok = T0TOK; wsf = true; }
    else { hb = bi - 128; tokbase = T0TOK; ntok = HTOK2; ismrg = true; }
  }
  const int b    = hb >> 6;
  const int nv   = (hb >> 1) & 31;
  const int half = hb & 1;
  const int nk   = nv >> 1;
  const int t    = threadIdx.x;
  const int lane = t & 63, w = t >> 6;
  const int lr   = lane & 15, hk = lane >> 4;

  for (int i = t; i < 128*40; i += 512) KT[i] = 0;
  for (int i = t; i < 16*40;  i += 512) Wl[i] = 0;
  for (int i = t; i < 64*136; i += 512){
    S0h[i] = 0; S0l[i] = 0;
    if (ismrg){ T0h[i] = 0; T0l[i] = 0; }
  }
  __syncthreads();
  if (ismrg && t < 64) T0h[t*136 + half*64 + t] = (ushort_t)0x3F80;  // bf16(1.0) identity

  const int dt  = w >> 1;
  const int dkb = (w & 1) * 4;
  const int ot  = w - 4;
  const int st  = t >> 5, sdk = (t & 31) * 4;
  const size_t bt0 = (size_t)b*SEQ + tokbase;
  const int mytile = (w < 4) ? w : (w - 4);

  f32x4 S[4], T[4];
  #pragma unroll
  for (int tt=0;tt<4;tt++)
    #pragma unroll
    for (int r=0;r<4;r++){
      S[tt][r] = 0.f;
      T[tt][r] = (ismrg && ((dkb+tt)*16 + hk*4 + r) == (half*64 + dt*16 + lr)) ? 1.f : 0.f;
    }

  // -------- prologue --------
  uint2 kreg = *(const uint2*)(qkv + (bt0+st)*CONVD + 2048 + nk*128 + sdk);
  bf16x8 qf[4];
  if (w >= 4){
    const ushort_t* qrow = qkv + (bt0+lr)*CONVD + nk*128 + hk*8;
    #pragma unroll
    for (int ks=0;ks<4;ks++) qf[ks] = *(const bf16x8*)(qrow + ks*32);
  }
  ushort_t vreg[4] = {0,0,0,0};
  if (w < 4){
    #pragma unroll
    for (int r=0;r<4;r++)
      vreg[r] = qkv[(bt0+hk*4+r)*CONVD + 4096 + nv*128 + half*64 + w*16 + lr];
  }
  {
    float2 gb = make_float2(0.f,0.f);
    if (w==1 && lane<16) gb = egb[(bt0+lane)*NV_ + nv];
    *(uint2*)&Kl[st*136 + sdk] = kreg;
    if (w==1 && lane<16){
      float c = gb.x;
      #pragma unroll
      for (int o=1;o<16;o<<=1){ float tv = __shfl_up(c, o, 16); if (lane >= o) c += tv; }
      clB[lane] = c; blB[lane] = gb.y; eclB[lane] = __expf(c);
      float c15 = __shfl(c, 15, 16);
      kslB[lane] = __expf(c15 - c);
      if (lane==0) c15B[0] = c15;
    }
  }
  __syncthreads();

  int pb = 0;
  for (int base = 0; base < ntok; base += CCH){
    const int nbase = (base + CCH < ntok) ? base + CCH : base;
    const int pb16 = pb*16;

    // ================= phase 1: products + A/W/u/KT builds =================
    bf16x8 kf[4];
    if (w <= 4){
      #pragma unroll
      for (int ks=0;ks<4;ks++) kf[ks] = *(const bf16x8*)&Kl[lr*136 + hk*8 + ks*32];
    }
    f32x4 ph = (f32x4){0.f,0.f,0.f,0.f}, pl = ph, phA = ph, plA = ph;
    __builtin_amdgcn_s_setprio(1);
    #pragma unroll
    for (int ks=0;ks<4;ks++){
      bf16x8 xf = (w < 4) ? kf[ks] : qf[ks];
      bf16x8 yh = *(const bf16x8*)&S0h[(mytile*16+lr)*136 + hk*8 + ks*32];
      bf16x8 yl = *(const bf16x8*)&S0l[(mytile*16+lr)*136 + hk*8 + ks*32];
      ph = __builtin_amdgcn_mfma_f32_16x16x32_bf16(xf, yh, ph, 0,0,0);
      pl = __builtin_amdgcn_mfma_f32_16x16x32_bf16(xf, yl, pl, 0,0,0);
    }
    if (ismrg){
      #pragma unroll
      for (int ks=0;ks<4;ks++){
        bf16x8 xf = (w < 4) ? kf[ks] : qf[ks];
        bf16x8 yh = *(const bf16x8*)&T0h[(mytile*16+lr)*136 + hk*8 + ks*32];
        bf16x8 yl = *(const bf16x8*)&T0l[(mytile*16+lr)*136 + hk*8 + ks*32];
        phA = __builtin_amdgcn_mfma_f32_16x16x32_bf16(xf, yh, phA, 0,0,0);
        plA = __builtin_amdgcn_mfma_f32_16x16x32_bf16(xf, yl, plA, 0,0,0);
      }
    }
    __builtin_amdgcn_s_setprio(0);
    if (w == 1){ // A build
      f32x4 a = (f32x4){0.f,0.f,0.f,0.f};
      #pragma unroll
      for (int ks=0;ks<4;ks++) a = __builtin_amdgcn_mfma_f32_16x16x32_bf16(kf[ks], kf[ks], a, 0,0,0);
      #pragma unroll
      for (int r=0;r<4;r++){
        int i = hk*4 + r, j = lr;
        Al[i*20 + j] = (j < i) ? blB[pb16+i]*__expf(clB[pb16+i]-clB[pb16+j])*a[r] : 0.f;
      }
    }
    if (w == 4){ // W build
      f32x4 a = (f32x4){0.f,0.f,0.f,0.f};
      #pragma unroll
      for (int ks=0;ks<4;ks++) a = __builtin_amdgcn_mfma_f32_16x16x32_bf16(qf[ks], kf[ks], a, 0,0,0);
      #pragma unroll
      for (int r=0;r<4;r++){
        int i = hk*4 + r, j = lr;
        float val = (j <= i) ? __expf(clB[pb16+i]-clB[pb16+j])*a[r] : 0.f;
        Wl[i*40 + j] = f2bf(val);
      }
    }
    if (w < 4){ // u builds (real; aug has v=0)
      float4 uu;
      #pragma unroll
      for (int r=0;r<4;r++){
        int i = hk*4 + r;
        ((float*)&uu)[r] = blB[pb16+i]*(bf2f(vreg[r]) - eclB[pb16+i]*(ph[r] + pl[r]));
      }
      *(float4*)&Ul[(w*16 + lr)*20 + hk*4] = uu;
      if (ismrg){
        float4 ua;
        #pragma unroll
        for (int r=0;r<4;r++){
          int i = hk*4 + r;
          ((float*)&ua)[r] = -blB[pb16+i]*eclB[pb16+i]*(phA[r] + plA[r]);
        }
        *(float4*)&Ul[(64 + w*16 + lr)*20 + hk*4] = ua;
      }
    }
    if (w == 2 || w == 3){ // K'^T build
      int dk = t & 127;
      #pragma unroll
      for (int j=0;j<16;j+=2){
        unsigned p0 = f2bf(kslB[pb16+j]  * bf2f(Kl[j*136     + dk]));
        unsigned p1 = f2bf(kslB[pb16+j+1]* bf2f(Kl[(j+1)*136 + dk]));
        *(unsigned*)&KT[dk*40 + j] = p0 | (p1 << 16);
      }
    }
    __syncthreads();   // B3: A,W,u,KT ready

    // ================= phase 2: prefetch + per-wave register substitutions ====
    kreg = *(const uint2*)(qkv + (bt0+nbase+st)*CONVD + 2048 + nk*128 + sdk);
    if (w >= 4){
      const ushort_t* qrow = qkv + (bt0 + nbase + lr)*CONVD + nk*128 + hk*8;
      #pragma unroll
      for (int ks=0;ks<4;ks++) qf[ks] = *(const bf16x8*)(qrow + ks*32);
    }
    if (w < 4){
      #pragma unroll
      for (int r=0;r<4;r++)
        vreg[r] = qkv[(bt0+nbase+hk*4+r)*CONVD + 4096 + nv*128 + half*64 + w*16 + lr];
    }
    float2 ebn = make_float2(0.f,0.f);
    if (w==1 && lane<16) ebn = egb[(bt0+nbase+lane)*NV_ + nv];
    bf16x8 yf[4];
    #pragma unroll
    for (int tt=0;tt<4;tt++) yf[tt] = *(const bf16x8*)&KT[((dkb+tt)*16+lr)*40 + hk*8];
    bf16x8 wfr;
    if (w >= 4) wfr = *(const bf16x8*)&Wl[lr*40 + hk*8];

    float dtmp[16];
    auto fsub_reg = [&](int colrow){   // solve (I+A)d = u for column `colrow` into dtmp (static idx only)
      #pragma unroll
      for (int q=0;q<4;q++){
        float4 dd = *(const float4*)&Ul[colrow*20 + q*4];
        dtmp[4*q]=dd.x; dtmp[4*q+1]=dd.y; dtmp[4*q+2]=dd.z; dtmp[4*q+3]=dd.w;
      }
      #pragma unroll
      for (int rb=0;rb<4;rb++){
        float p0=0.f,p1=0.f,p2=0.f,p3=0.f;
        #pragma unroll
        for (int jb=0;jb<rb;jb++){
          float4 A0 = *(const float4*)&Al[(rb*4+0)*20 + jb*4];
          float4 A1 = *(const float4*)&Al[(rb*4+1)*20 + jb*4];
          float4 A2 = *(const float4*)&Al[(rb*4+2)*20 + jb*4];
          float4 A3 = *(const float4*)&Al[(rb*4+3)*20 + jb*4];
          p0 += A0.x*dtmp[jb*4]+A0.y*dtmp[jb*4+1]+A0.z*dtmp[jb*4+2]+A0.w*dtmp[jb*4+3];
          p1 += A1.x*dtmp[jb*4]+A1.y*dtmp[jb*4+1]+A1.z*dtmp[jb*4+2]+A1.w*dtmp[jb*4+3];
          p2 += A2.x*dtmp[jb*4]+A2.y*dtmp[jb*4+1]+A2.z*dtmp[jb*4+2]+A2.w*dtmp[jb*4+3];
          p3 += A3.x*dtmp[jb*4]+A3.y*dtmp[jb*4+1]+A3.z*dtmp[jb*4+2]+A3.w*dtmp[jb*4+3];
        }
        const int r0 = rb*4;
        dtmp[r0+0] -= p0;
        dtmp[r0+1] -= p1 + Al[(r0+1)*20+r0]*dtmp[r0];
        dtmp[r0+2] -= p2 + Al[(r0+2)*20+r0]*dtmp[r0] + Al[(r0+2)*20+r0+1]*dtmp[r0+1];
        dtmp[r0+3] -= p3 + Al[(r0+3)*20+r0]*dtmp[r0] + Al[(r0+3)*20+r0+1]*dtmp[r0+1] + Al[(r0+3)*20+r0+2]*dtmp[r0+2];
      }
    };
    // VALUE-select on hk (compile-time array indices only -> stays in registers; rule #20)
    auto mkfrag = [&]()->bf16x8{
      union { bf16x8 v; ushort_t u[8]; } rlo, rhi;
      #pragma unroll
      for (int j=0;j<8;j++){ rlo.u[j] = f2bf(dtmp[j]); rhi.u[j] = f2bf(dtmp[8+j]); }
      bf16x8 z = {};
      return (hk == 0) ? rlo.v : ((hk == 1) ? rhi.v : z);
    };

    __builtin_amdgcn_s_setprio(1);
    fsub_reg(dt*16 + lr);               // state-update column
    bf16x8 fB = mkfrag();
    bf16x8 fO = {};
    if (w >= 4){ fsub_reg(ot*16 + lr); fO = mkfrag(); }
    bf16x8 fBA = {}, fOA = {};
    if (ismrg){
      fsub_reg(64 + dt*16 + lr); fBA = mkfrag();
      if (w >= 4){ fsub_reg(64 + ot*16 + lr); fOA = mkfrag(); }
    }
    __builtin_amdgcn_s_setprio(0);

    // ================= phase 3: O + state updates + writebacks + next staging =================
    if (w >= 4){
      f32x4 oo = __builtin_amdgcn_mfma_f32_16x16x32_bf16(wfr, fO, (f32x4){0.f,0.f,0.f,0.f}, 0,0,0);
      #pragma unroll
      for (int r=0;r<4;r++){
        int i = hk*4 + r;
        outc[((bt0+base+i)*NV_ + nv)*(size_t)DV_ + half*64 + ot*16 + lr] = oo[r] + eclB[pb16+i]*(ph[r] + pl[r]);
      }
      if (ismrg){
        f32x4 oo2 = __builtin_amdgcn_mfma_f32_16x16x32_bf16(wfr, fOA, (f32x4){0.f,0.f,0.f,0.f}, 0,0,0);
        #pragma unroll
        for (int r=0;r<4;r++){
          int i = hk*4 + r;
          oaug[(((size_t)(b*NV_+nv))*HTOK2 + base + i)*128 + half*64 + ot*16 + lr]
            = f2bf(oo2[r] + eclB[pb16+i]*(phA[r] + plA[r]));
        }
      }
    }
    {
      float g15 = __expf(c15B[pb]);
      __builtin_amdgcn_s_setprio(1);
      #pragma unroll
      for (int tt=0;tt<4;tt++){
        f32x4 s = S[tt];
        s[0]*=g15; s[1]*=g15; s[2]*=g15; s[3]*=g15;
        S[tt] = __builtin_amdgcn_mfma_f32_16x16x32_bf16(yf[tt], fB, s, 0,0,0);
      }
      if (ismrg){
        #pragma unroll
        for (int tt=0;tt<4;tt++){
          f32x4 s = T[tt];
          s[0]*=g15; s[1]*=g15; s[2]*=g15; s[3]*=g15;
          T[tt] = __builtin_amdgcn_mfma_f32_16x16x32_bf16(yf[tt], fBA, s, 0,0,0);
        }
      }
      __builtin_amdgcn_s_setprio(0);
    }
    {
      const int dv = dt*16 + lr;
      #pragma unroll
      for (int tt=0;tt<4;tt++){
        const int dk0 = (dkb+tt)*16 + hk*4;
        {
          float s0=S[tt][0], s1=S[tt][1], s2=S[tt][2], s3=S[tt][3];
          ushort_t h0=f2bf(s0), h1=f2bf(s1), h2=f2bf(s2), h3=f2bf(s3);
          *(uint2*)&S0h[dv*136 + dk0] = make_uint2((unsigned)h0 | ((unsigned)h1<<16),
                                                   (unsigned)h2 | ((unsigned)h3<<16));
          *(uint2*)&S0l[dv*136 + dk0] = make_uint2((unsigned)f2bf(s0-bf2f(h0)) | ((unsigned)f2bf(s1-bf2f(h1))<<16),
                                                   (unsigned)f2bf(s2-bf2f(h2)) | ((unsigned)f2bf(s3-bf2f(h3))<<16));
        }
        if (ismrg){
          float s0=T[tt][0], s1=T[tt][1], s2=T[tt][2], s3=T[tt][3];
          ushort_t h0=f2bf(s0), h1=f2bf(s1), h2=f2bf(s2), h3=f2bf(s3);
          *(uint2*)&T0h[dv*136 + dk0] = make_uint2((unsigned)h0 | ((unsigned)h1<<16),
                                                   (unsigned)h2 | ((unsigned)h3<<16));
          *(uint2*)&T0l[dv*136 + dk0] = make_uint2((unsigned)f2bf(s0-bf2f(h0)) | ((unsigned)f2bf(s1-bf2f(h1))<<16),
                                                   (unsigned)f2bf(s2-bf2f(h2)) | ((unsigned)f2bf(s3-bf2f(h3))<<16));
        }
      }
    }
    *(uint2*)&Kl[st*136 + sdk] = kreg;
    if (w==1 && lane<16){
      float c = ebn.x;
      #pragma unroll
      for (int o=1;o<16;o<<=1){ float tv = __shfl_up(c, o, 16); if (lane >= o) c += tv; }
      int q16 = (pb^1)*16;
      clB[q16+lane] = c; blB[q16+lane] = ebn.y; eclB[q16+lane] = __expf(c);
      float c15 = __shfl(c, 15, 16);
      kslB[q16+lane] = __expf(c15 - c);
      if (lane==0) c15B[pb^1] = c15;
    }
    __syncthreads();   // B5
    pb ^= 1;
  }

  if (wsf){
    for (int i = t; i < 64*128; i += 512){
      int dvl = i >> 7, dk = i & 127;
      size_t row = ((size_t)(b*NV_+nv)*128 + half*64 + dvl)*256;
      Sfin[row + dk]       = S0h[dvl*136 + dk];
      Sfin[row + 128 + dk] = S0l[dvl*136 + dk];
    }
  }
}

// ---------------- correction: core[tokens T0TOK..SEQ) += oaug @ Sfin^T (per head) ----------------
__global__ __launch_bounds__(256) void corr_gemm(const ushort_t* __restrict__ oaug, const ushort_t* __restrict__ Sfin,
                                                 float* __restrict__ core){
  __shared__ ushort_t As[128][32];
  __shared__ ushort_t Bs[128][32];
  const int head = blockIdx.y;
  const int m0 = blockIdx.x * 128;
  const int b = head >> 5, nv = head & 31;
  const int t = threadIdx.x, lane = t & 63, w = t >> 6;
  const int wm = w >> 1, wn = w & 1;
  const int srow = lane >> 2, scol = (lane & 3) * 8;
  const ushort_t* Abase = oaug + (size_t)head*HTOK2*128;
  const ushort_t* Bbase = Sfin + (size_t)head*128*256;
  ushort_t* lA0 = &As[     w*16][0];
  ushort_t* lA1 = &As[64 + w*16][0];
  ushort_t* lB0 = &Bs[     w*16][0];
  ushort_t* lB1 = &Bs[64 + w*16][0];
  f32x4 acc[4][4];
  #pragma unroll
  for (int i=0;i<4;i++)
    #pragma unroll
    for (int j=0;j<4;j++) acc[i][j] = (f32x4){0.f,0.f,0.f,0.f};
  const int lr = lane & 15, lk = (lane >> 4) * 8;
  for (int k0 = 0; k0 < 256; k0 += 32){
    const int ka = k0 & 127;
    int ra0 = m0 +      w*16 + srow; if (ra0 >= HTOK2) ra0 = HTOK2 - 1;
    int ra1 = m0 + 64 + w*16 + srow; if (ra1 >= HTOK2) ra1 = HTOK2 - 1;
    __builtin_amdgcn_global_load_lds((const __attribute__((address_space(1))) void*)(Abase + (size_t)ra0*128 + ka + scol),
                                     (__attribute__((address_space(3))) void*)lA0, 16, 0, 0);
    __builtin_amdgcn_global_load_lds((const __attribute__((address_space(1))) void*)(Abase + (size_t)ra1*128 + ka + scol),
                                     (__attribute__((address_space(3))) void*)lA1, 16, 0, 0);
    __builtin_amdgcn_global_load_lds((const __attribute__((address_space(1))) void*)(Bbase + (size_t)(     w*16 + srow)*256 + k0 + scol),
                                     (__attribute__((address_space(3))) void*)lB0, 16, 0, 0);
    __builtin_amdgcn_global_load_lds((const __attribute__((address_space(1))) void*)(Bbase + (size_t)(64 + w*16 + srow)*256 + k0 + scol),
                                     (__attribute__((address_space(3))) void*)lB1, 16, 0, 0);
    __syncthreads();
    bf16x8 af[4], bfv[4];
    #pragma unroll
    for (int i=0;i<4;i++) af[i]  = *(const bf16x8*)&As[wm*64 + i*16 + lr][lk];
    #pragma unroll
    for (int j=0;j<4;j++) bfv[j] = *(const bf16x8*)&Bs[wn*64 + j*16 + lr][lk];
    #pragma unroll
    for (int i=0;i<4;i++)
      #pragma unroll
      for (int j=0;j<4;j++)
        acc[i][j] = __builtin_amdgcn_mfma_f32_16x16x32_bf16(af[i], bfv[j], acc[i][j], 0, 0, 0);
    __syncthreads();
  }
  const int lg = lane >> 4;
  #pragma unroll
  for (int i=0;i<4;i++)
    #pragma unroll
    for (int j=0;j<4;j++)
      #pragma unroll
      for (int r=0;r<4;r++){
        int m = m0 + wm*64 + i*16 + lg*4 + r;
        int n = wn*64 + j*16 + lr;
        if (m < HTOK2){
          float* p = &core[(((size_t)b*SEQ + T0TOK + m)*NV_ + nv)*(size_t)DV_ + n];
          *p += acc[i][j][r];
        }
      }
}

// ---------------- gated RMSNorm -> bf16 ----------------
__global__ __launch_bounds__(128) void gatenorm_kernel(const float* __restrict__ outc, const ushort_t* __restrict__ qkvz,
                                                       const float* __restrict__ norm_w, ushort_t* __restrict__ gated){
  __shared__ float red[2];
  const int blk = blockIdx.x;
  const int nv = blk & 31;
  const size_t bt = (size_t)(blk >> 5);
  const int dv = threadIdx.x;
  float xv = outc[(bt*NV_ + nv)*(size_t)DV_ + dv];
  float ss = xv*xv;
  #pragma unroll
  for (int o=1;o<64;o<<=1) ss += __shfl_xor(ss, o);
  if ((threadIdx.x & 63)==0) red[threadIdx.x>>6] = ss;
  __syncthreads();
  float tot = red[0]+red[1];
  float xn = xv * rsqrtf(tot*(1.f/128.f) + 1e-6f) * norm_w[dv];
  int nk = nv>>1, r = nv&1;
  float z = bf2f(qkvz[bt*NQKVZ + nk*768 + 512 + r*128 + dv]);
  gated[bt*(size_t)4096 + nv*128 + dv] = f2bf(siluf_(z)*xn);
}

extern "C" void kernel_launch(void* const* d_in, const int* in_sizes, int n_in,
                              void* d_out, int out_size, void* d_ws, size_t ws_size,
                              hipStream_t stream){
  (void)in_sizes; (void)n_in; (void)out_size;
  const float* x      = (const float*)d_in[0];
  const float* W_qkvz = (const float*)d_in[1];
  const float* W_ba   = (const float*)d_in[2];
  const float* conv_w = (const float*)d_in[3];
  const float* dt_bias= (const float*)d_in[4];
  const float* A_log  = (const float*)d_in[5];
  const float* norm_w = (const float*)d_in[6];
  const float* W_out  = (const float*)d_in[7];
  float* outp = (float*)d_out;

  char* w = (char*)d_ws;
  const size_t R0 = 0;
  const size_t R1 = 100663296;
  const size_t R2 = R1 + 67108864;
  const size_t R3 = R2 + 67108864;
  const size_t R4 = R3 + 2097152;
  const size_t NEED_SP = R4 + 16777216 + 4194304;
  ushort_t* qkvz_bf = (ushort_t*)(w + R0);
  ushort_t* xb      = (ushort_t*)(w + R1);
  ushort_t* wqt     = (ushort_t*)(w + R1 + 16777216);
  ushort_t* qkv_bf  = (ushort_t*)(w + R1);
  ushort_t* gated   = (ushort_t*)(w + R1);
  float*    core    = (float*)   (w + R2);
  ushort_t* wot     = (ushort_t*)(w + R2);
  float*    ba      = (float*)   (w + R3);
  float2*   egb     = (float2*)  (w + R3 + 1048576);
  ushort_t* oaug    = (ushort_t*)(w + R4);
  ushort_t* Sfin    = (ushort_t*)(w + R4 + 16777216);

  hipError_t e1 = hipFuncSetAttribute((const void*)gemm_big<1>, hipFuncAttributeMaxDynamicSharedMemorySize, 98304);
  hipError_t e2 = hipFuncSetAttribute((const void*)gemm_big2<0>, hipFuncAttributeMaxDynamicSharedMemorySize, 73728);
  hipError_t e3 = hipFuncSetAttribute((const void*)recurrence_chunked, hipFuncAttributeMaxDynamicSharedMemorySize, RLDSZ);
  (void)e1; (void)e2;
  const bool seqpar = (ws_size >= NEED_SP) && (e3 == hipSuccess);

  cast_x_kernel<<<(MTOT*HID/4 + 255)/256, 256, 0, stream>>>(x, xb, MTOT*HID/4);
  transpose_cast<<<dim3(NQKVZ/64, HID/64), 256, 0, stream>>>(W_qkvz, wqt, HID, NQKVZ);
  gemm_big<1><<<dim3(NQKVZ/256, MTOT/256), 512, 98304, stream>>>(xb, wqt, (void*)qkvz_bf, MTOT, NQKVZ, HID);
  gemm_ba<<<MTOT/4, 256, 0, stream>>>(x, W_ba, ba);
  gbeta_kernel<<<(MTOT*NV_+255)/256, 256, 0, stream>>>(ba, A_log, dt_bias, egb);
  conv_norm_kernel<<<(MTOT/CT)*16, 256, 0, stream>>>(qkvz_bf, conv_w, qkv_bf);
  if (seqpar){
    recurrence_chunked<<<256, 512, RLDSZ, stream>>>(qkv_bf, egb, core, oaug, Sfin, 1);
    corr_gemm<<<dim3((HTOK2 + 127)/128, 64), 256, 0, stream>>>(oaug, Sfin, core);
  } else {
    recurrence_chunked<<<128, 512, RLDSZ, stream>>>(qkv_bf, egb, core, oaug, Sfin, 0);
  }
  gatenorm_kernel<<<MTOT*NV_, 128, 0, stream>>>(core, qkvz_bf, norm_w, gated);
  transpose_cast<<<dim3(2048/64, 4096/64), 256, 0, stream>>>(W_out, wot, 4096, 2048);
  gemm_big2<0><<<dim3(2048/128, MTOT/256), 512, 73728, stream>>>(gated, wot, (void*)outp, MTOT, 2048, 4096);
}

// Round 23
// 849.917 us; speedup vs baseline: 1.8744x; 1.8744x over previous
//
#include <hip/hip_runtime.h>
#include <stdint.h>

#define B_    2
#define SEQ   2048
#define HID   2048
#define NK_   16
#define NV_   32
#define DK_   128
#define DV_   128
#define NQKVZ 12288
#define CONVD 8192
#define MTOT  (B_*SEQ)   // 4096
#define CCH   16         // recurrence sub-chunk length
#define T0TOK 1216       // partition 0 length (76 chunks, single chain) -- proven balance (r19: 270us)
#define HTOK2 832        // partition 1 length (52 chunks, merged dual chain)
#define CT    8          // conv rolling tile
#define RLDSZ 110592     // recurrence dynamic LDS

typedef unsigned short ushort_t;
typedef __bf16 bf16x8 __attribute__((ext_vector_type(8)));
typedef float  f32x4  __attribute__((ext_vector_type(4)));
typedef unsigned short us4 __attribute__((ext_vector_type(4)));

__device__ __forceinline__ ushort_t f2bf(float f){
  union { float f; unsigned u; } v; v.f = f;
  unsigned r = v.u + 0x7FFFu + ((v.u >> 16) & 1u);
  return (ushort_t)(r >> 16);
}
__device__ __forceinline__ float bf2f(ushort_t u){
  union { unsigned u; float f; } v; v.u = ((unsigned)u) << 16; return v.f;
}
__device__ __forceinline__ float sigmoidf_(float x){ return 1.f/(1.f+__expf(-x)); }
__device__ __forceinline__ float siluf_(float x){ return x*sigmoidf_(x); }

// ---------------- cast x -> bf16 ----------------
__global__ void cast_x_kernel(const float* __restrict__ x, ushort_t* __restrict__ xb, int n4){
  int i = blockIdx.x*256 + threadIdx.x;
  if (i >= n4) return;
  float4 v = ((const float4*)x)[i];
  us4 o; o[0]=f2bf(v.x); o[1]=f2bf(v.y); o[2]=f2bf(v.z); o[3]=f2bf(v.w);
  ((us4*)xb)[i] = o;
}

// ---------------- transpose + cast W[K][N] -> Wt[N][K] bf16 ----------------
__global__ __launch_bounds__(256) void transpose_cast(const float* __restrict__ W, ushort_t* __restrict__ Wt,
                                                      int K, int N){
  __shared__ float tile[64][65];
  int n0 = blockIdx.x*64, k0 = blockIdx.y*64;
  int tx = threadIdx.x & 63, ty = threadIdx.x >> 6;
  #pragma unroll
  for (int i=0;i<16;i++){
    int kr = ty + i*4;
    tile[kr][tx] = W[(size_t)(k0+kr)*N + n0+tx];
  }
  __syncthreads();
  #pragma unroll
  for (int i=0;i<16;i++){
    int nr = ty + i*4;
    Wt[(size_t)(n0+nr)*K + k0+tx] = f2bf(tile[tx][nr]);
  }
}

// ---------------- big-tile GEMM: 256x256, BK=32, 3-deep pipeline, counted vmcnt ----------------
template<int OUTBF>
__global__ __launch_bounds__(512, 2) void gemm_big(const ushort_t* __restrict__ A, const ushort_t* __restrict__ Bt,
                                                   void* __restrict__ Cv, int M, int N, int K){
  extern __shared__ ushort_t dynlds[];
  ushort_t* SA = dynlds;
  ushort_t* SB = dynlds + 3*8192;
  const int t = threadIdx.x;
  const int lane = t & 63, w = t >> 6;
  const int wm = w >> 2, wn = w & 3;
  const int lr = lane & 15, hk = lane >> 4;
  const int gx = gridDim.x;
  const int nwg = gx * gridDim.y;
  const int flat = blockIdx.y*gx + blockIdx.x;
  const int cpx = nwg >> 3;
  const int swzb = (flat & 7)*cpx + (flat >> 3);
  const int m0 = (swzb / gx) * 256, n0 = (swzb % gx) * 256;

  int srow[2], scol[2];
  #pragma unroll
  for (int q=0;q<2;q++){
    int p  = (w*2+q)*1024 + lane*16;
    int lg = p ^ (((p>>9)&1)<<5);
    srow[q] = lg >> 6;
    scol[q] = (lg & 63) >> 1;
  }
  int phA[8], phB[4];
  #pragma unroll
  for (int mi=0;mi<8;mi++){
    int lg = (wm*128 + mi*16 + lr)*64 + hk*16;
    phA[mi] = lg ^ (((lg>>9)&1)<<5);
  }
  #pragma unroll
  for (int ni=0;ni<4;ni++){
    int lg = (wn*64 + ni*16 + lr)*64 + hk*16;
    phB[ni] = lg ^ (((lg>>9)&1)<<5);
  }

  auto stage = [&](int j, int bufb){
    #pragma unroll
    for (int q=0;q<2;q++)
      __builtin_amdgcn_global_load_lds(
        (const __attribute__((address_space(1))) void*)(A + (size_t)(m0+srow[q])*K + j*32 + scol[q]),
        (__attribute__((address_space(3))) void*)(SA + bufb*8192 + (w*2+q)*512), 16, 0, 0);
    #pragma unroll
    for (int q=0;q<2;q++)
      __builtin_amdgcn_global_load_lds(
        (const __attribute__((address_space(1))) void*)(Bt + (size_t)(n0+srow[q])*K + j*32 + scol[q]),
        (__attribute__((address_space(3))) void*)(SB + bufb*8192 + (w*2+q)*512), 16, 0, 0);
  };

  f32x4 acc[8][4];
  #pragma unroll
  for (int mi=0;mi<8;mi++)
    #pragma unroll
    for (int ni=0;ni<4;ni++) acc[mi][ni] = (f32x4){0.f,0.f,0.f,0.f};

  const int NT = K >> 5;
  stage(0, 0);
  stage(1, 1);
  asm volatile("s_waitcnt vmcnt(4)" ::: "memory");
  __builtin_amdgcn_s_barrier();
  __builtin_amdgcn_sched_barrier(0);

  int cur = 0;
  for (int j = 0; j < NT; ++j){
    int nb = cur + 2; if (nb >= 3) nb -= 3;
    if (j + 2 < NT) stage(j+2, nb);
    const char* bA = (const char*)(SA + cur*8192);
    const char* bB = (const char*)(SB + cur*8192);
    bf16x8 af[8], bfv[4];
    #pragma unroll
    for (int mi=0;mi<8;mi++) af[mi]  = *(const bf16x8*)(bA + phA[mi]);
    #pragma unroll
    for (int ni=0;ni<4;ni++) bfv[ni] = *(const bf16x8*)(bB + phB[ni]);
    #pragma unroll
    for (int mi=0;mi<8;mi++)
      #pragma unroll
      for (int ni=0;ni<4;ni++)
        acc[mi][ni] = __builtin_amdgcn_mfma_f32_16x16x32_bf16(af[mi], bfv[ni], acc[mi][ni], 0, 0, 0);
    if (j + 2 < NT){
      asm volatile("s_waitcnt vmcnt(4)" ::: "memory");
      __builtin_amdgcn_s_barrier();
      __builtin_amdgcn_sched_barrier(0);
    } else if (j + 1 < NT){
      asm volatile("s_waitcnt vmcnt(0)" ::: "memory");
      __builtin_amdgcn_s_barrier();
      __builtin_amdgcn_sched_barrier(0);
    }
    cur = cur + 1; if (cur >= 3) cur -= 3;
  }

  #pragma unroll
  for (int mi=0;mi<8;mi++)
    #pragma unroll
    for (int ni=0;ni<4;ni++)
      #pragma unroll
      for (int r=0;r<4;r++){
        int m = m0 + wm*128 + mi*16 + hk*4 + r;
        int n = n0 + wn*64  + ni*16 + lr;
        if (OUTBF) ((ushort_t*)Cv)[(size_t)m*N + n] = f2bf(acc[mi][ni][r]);
        else       ((float*)Cv)[(size_t)m*N + n]    = acc[mi][ni][r];
      }
}

// ---------------- big-tile GEMM variant: 256M x 128N ----------------
template<int OUTBF>
__global__ __launch_bounds__(512, 2) void gemm_big2(const ushort_t* __restrict__ A, const ushort_t* __restrict__ Bt,
                                                    void* __restrict__ Cv, int M, int N, int K){
  extern __shared__ ushort_t dynlds[];
  ushort_t* SA = dynlds;
  ushort_t* SB = dynlds + 3*8192;
  const int t = threadIdx.x;
  const int lane = t & 63, w = t >> 6;
  const int wm = w >> 1, wn = w & 1;
  const int lr = lane & 15, hk = lane >> 4;
  const int gx = gridDim.x;
  const int nwg = gx * gridDim.y;
  const int flat = blockIdx.y*gx + blockIdx.x;
  const int cpx = nwg >> 3;
  const int swzb = (flat & 7)*cpx + (flat >> 3);
  const int m0 = (swzb / gx) * 256, n0 = (swzb % gx) * 128;

  int srA[2], scA[2];
  #pragma unroll
  for (int q=0;q<2;q++){
    int p  = (w*2+q)*1024 + lane*16;
    int lg = p ^ (((p>>9)&1)<<5);
    srA[q] = lg >> 6;
    scA[q] = (lg & 63) >> 1;
  }
  int srB, scB;
  {
    int p  = w*1024 + lane*16;
    int lg = p ^ (((p>>9)&1)<<5);
    srB = lg >> 6;
    scB = (lg & 63) >> 1;
  }
  int phA[4], phB[4];
  #pragma unroll
  for (int mi=0;mi<4;mi++){
    int lg = (wm*64 + mi*16 + lr)*64 + hk*16;
    phA[mi] = lg ^ (((lg>>9)&1)<<5);
  }
  #pragma unroll
  for (int ni=0;ni<4;ni++){
    int lg = (wn*64 + ni*16 + lr)*64 + hk*16;
    phB[ni] = lg ^ (((lg>>9)&1)<<5);
  }

  auto stage = [&](int j, int bufb){
    #pragma unroll
    for (int q=0;q<2;q++)
      __builtin_amdgcn_global_load_lds(
        (const __attribute__((address_space(1))) void*)(A + (size_t)(m0+srA[q])*K + j*32 + scA[q]),
        (__attribute__((address_space(3))) void*)(SA + bufb*8192 + (w*2+q)*512), 16, 0, 0);
    __builtin_amdgcn_global_load_lds(
        (const __attribute__((address_space(1))) void*)(Bt + (size_t)(n0+srB)*K + j*32 + scB),
        (__attribute__((address_space(3))) void*)(SB + bufb*4096 + w*512), 16, 0, 0);
  };

  f32x4 acc[4][4];
  #pragma unroll
  for (int mi=0;mi<4;mi++)
    #pragma unroll
    for (int ni=0;ni<4;ni++) acc[mi][ni] = (f32x4){0.f,0.f,0.f,0.f};

  const int NT = K >> 5;
  stage(0, 0);
  stage(1, 1);
  asm volatile("s_waitcnt vmcnt(3)" ::: "memory");
  __builtin_amdgcn_s_barrier();
  __builtin_amdgcn_sched_barrier(0);

  int cur = 0;
  for (int j = 0; j < NT; ++j){
    int nb = cur + 2; if (nb >= 3) nb -= 3;
    if (j + 2 < NT) stage(j+2, nb);
    const char* bA = (const char*)(SA + cur*8192);
    const char* bB = (const char*)(SB + cur*4096);
    bf16x8 af[4], bfv[4];
    #pragma unroll
    for (int mi=0;mi<4;mi++) af[mi]  = *(const bf16x8*)(bA + phA[mi]);
    #pragma unroll
    for (int ni=0;ni<4;ni++) bfv[ni] = *(const bf16x8*)(bB + phB[ni]);
    #pragma unroll
    for (int mi=0;mi<4;mi++)
      #pragma unroll
      for (int ni=0;ni<4;ni++)
        acc[mi][ni] = __builtin_amdgcn_mfma_f32_16x16x32_bf16(af[mi], bfv[ni], acc[mi][ni], 0, 0, 0);
    if (j + 2 < NT){
      asm volatile("s_waitcnt vmcnt(3)" ::: "memory");
      __builtin_amdgcn_s_barrier();
      __builtin_amdgcn_sched_barrier(0);
    } else if (j + 1 < NT){
      asm volatile("s_waitcnt vmcnt(0)" ::: "memory");
      __builtin_amdgcn_s_barrier();
      __builtin_amdgcn_sched_barrier(0);
    }
    cur = cur + 1; if (cur >= 3) cur -= 3;
  }

  #pragma unroll
  for (int mi=0;mi<4;mi++)
    #pragma unroll
    for (int ni=0;ni<4;ni++)
      #pragma unroll
      for (int r=0;r<4;r++){
        int m = m0 + wm*64 + mi*16 + hk*4 + r;
        int n = n0 + wn*64 + ni*16 + lr;
        if (OUTBF) ((ushort_t*)Cv)[(size_t)m*N + n] = f2bf(acc[mi][ni][r]);
        else       ((float*)Cv)[(size_t)m*N + n]    = acc[mi][ni][r];
      }
}

// ---------------- ba = x @ W_ba (fp32, N=64) ----------------
__global__ __launch_bounds__(256) void gemm_ba(const float* __restrict__ x, const float* __restrict__ Wba,
                                               float* __restrict__ ba){
  int lane = threadIdx.x & 63;
  int wid  = threadIdx.x >> 6;
  int row  = blockIdx.x*4 + wid;
  const float* xr = x + (size_t)row*HID;
  float acc = 0.f;
  for (int k=0;k<HID;k+=4){
    float4 xv = *(const float4*)&xr[k];
    acc += xv.x * Wba[(size_t)(k+0)*64 + lane];
    acc += xv.y * Wba[(size_t)(k+1)*64 + lane];
    acc += xv.z * Wba[(size_t)(k+2)*64 + lane];
    acc += xv.w * Wba[(size_t)(k+3)*64 + lane];
  }
  ba[(size_t)row*64 + lane] = acc;
}

// ---------------- conv(k=4) + SiLU + q/k RMS-norm (rolling window) ----------------
__global__ __launch_bounds__(256) void conv_norm_kernel(const ushort_t* __restrict__ qkvz, const float* __restrict__ conv_w,
                                                        ushort_t* __restrict__ qkv){
  const int blk = blockIdx.x;
  const int bt0 = (blk >> 4) * CT;
  const int ts0 = bt0 & (SEQ-1);
  const int gi = (blk & 15)*4 + (threadIdx.x >> 6);
  const int e2 = threadIdx.x & 63;
  const int dk = 2*e2;
  int col;
  if (gi < 16)       col = gi*768 + dk;
  else if (gi < 32)  col = (gi-16)*768 + 128 + dk;
  else { int nv = gi-32; col = (nv>>1)*768 + 256 + (nv&1)*128 + dk; }
  const int c = gi*128 + dk;
  const float4 w0 = *(const float4*)&conv_w[(size_t)c*4];
  const float4 w1 = *(const float4*)&conv_w[(size_t)(c+1)*4];
  ushort2 h0 = (ts0>=1) ? *(const ushort2*)&qkvz[(size_t)(bt0-3)*NQKVZ + col] : make_ushort2(0,0);
  ushort2 h1 = (ts0>=1) ? *(const ushort2*)&qkvz[(size_t)(bt0-2)*NQKVZ + col] : make_ushort2(0,0);
  ushort2 h2 = (ts0>=1) ? *(const ushort2*)&qkvz[(size_t)(bt0-1)*NQKVZ + col] : make_ushort2(0,0);
  const float scale = (gi < 16) ? (1.f/128.f) : 0.08838834764831845f;
  #pragma unroll
  for (int tt=0; tt<CT; ++tt){
    const int bt = bt0 + tt;
    ushort2 h3 = *(const ushort2*)&qkvz[(size_t)bt*NQKVZ + col];
    float y0 = siluf_(bf2f(h0.x)*w0.x + bf2f(h1.x)*w0.y + bf2f(h2.x)*w0.z + bf2f(h3.x)*w0.w);
    float y1 = siluf_(bf2f(h0.y)*w1.x + bf2f(h1.y)*w1.y + bf2f(h2.y)*w1.z + bf2f(h3.y)*w1.w);
    float o0 = y0, o1 = y1;
    if (gi < 32){
      float ss = y0*y0 + y1*y1;
      #pragma unroll
      for (int o=1;o<64;o<<=1) ss += __shfl_xor(ss, o);
      float rs = rsqrtf(ss*(1.f/128.f) + 1e-6f);
      o0 = y0*rs*scale; o1 = y1*rs*scale;
    }
    ushort2 ov; ov.x = f2bf(o0); ov.y = f2bf(o1);
    *(ushort2*)&qkv[(size_t)bt*CONVD + gi*128 + dk] = ov;
    h0 = h1; h1 = h2; h2 = h3;
  }
}

// ---------------- {g, beta} as float2 ----------------
__global__ void gbeta_kernel(const float* __restrict__ ba, const float* __restrict__ A_log,
                             const float* __restrict__ dt_bias, float2* __restrict__ egb){
  int idx = blockIdx.x*256 + threadIdx.x;
  if (idx >= MTOT*NV_) return;
  int nv = idx & 31;
  int bt = idx >> 5;
  int nk = nv >> 1, r = nv & 1;
  float bg = ba[(size_t)bt*64 + nk*4 + r];
  float ag = ba[(size_t)bt*64 + nk*4 + 2 + r];
  float ad = ag + dt_bias[nv];
  float sp = fmaxf(ad, 0.f) + log1pf(__expf(-fabsf(ad)));
  float g  = -__expf(A_log[nv]) * sp;
  egb[idx] = make_float2(g, sigmoidf_(bg));
}

// ---------------- chunked gated delta-rule, seq-parallel P=2 (asymmetric) with MERGED 2nd blocks ----------------
// Round-18/19 proven body: 3 barriers, w0/w1 LDS-DT substitution; T0TOK=1216 split (recurrence 270us).
__global__ __launch_bounds__(512) void recurrence_chunked(const ushort_t* __restrict__ qkv,
                                                          const float2* __restrict__ egb,
                                                          float* __restrict__ outc,
                                                          ushort_t* __restrict__ oaug,
                                                          ushort_t* __restrict__ Sfin,
                                                          int pmode){
  extern __shared__ char rlds[];
  ushort_t* Kl  = (ushort_t*)(rlds + 0);       // 16*136
  ushort_t* S0h = (ushort_t*)(rlds + 4352);    // 64*136
  ushort_t* S0l = (ushort_t*)(rlds + 21760);
  ushort_t* T0h = (ushort_t*)(rlds + 39168);   // aug state
  ushort_t* T0l = (ushort_t*)(rlds + 56576);
  ushort_t* KT  = (ushort_t*)(rlds + 73984);   // 128*40
  ushort_t* DT  = (ushort_t*)(rlds + 84224);   // 128*40 (rows 0-63 real, 64-127 aug)
  ushort_t* Wl  = (ushort_t*)(rlds + 94464);   // 16*40
  float*    Al  = (float*)   (rlds + 95744);   // 16*20
  float*    Ul  = (float*)   (rlds + 97024);   // 128*20
  float*    clB = (float*)   (rlds + 107264);  // [2][16]
  float*    blB = clB + 32;
  float*    eclB= clB + 64;
  float*    kslB= clB + 96;
  float*    c15B= clB + 128;                   // [2]

  const int bi = blockIdx.x;
  int hb, tokbase, ntok;
  bool ismrg = false, wsf = false;
  if (pmode == 0){ hb = bi; tokbase = 0; ntok = SEQ; }
  else {
    if (bi < 128){ hb = bi; tokbase = 0; ntok = T0TOK; wsf = true; }
    else { hb = bi - 128; tokbase = T0TOK; ntok = HTOK2; ismrg = true; }
  }
  const int b    = hb >> 6;
  const int nv   = (hb >> 1) & 31;
  const int half = hb & 1;
  const int nk   = nv >> 1;
  const int t    = threadIdx.x;
  const int lane = t & 63, w = t >> 6;
  const int lr   = lane & 15, hk = lane >> 4;

  for (int i = t; i < 128*40; i += 512){ KT[i] = 0; DT[i] = 0; }
  for (int i = t; i < 16*40;  i += 512) Wl[i] = 0;
  for (int i = t; i < 64*136; i += 512){
    S0h[i] = 0; S0l[i] = 0;
    if (ismrg){ T0h[i] = 0; T0l[i] = 0; }
  }
  __syncthreads();
  if (ismrg && t < 64) T0h[t*136 + half*64 + t] = (ushort_t)0x3F80;  // bf16(1.0) identity

  const int dt  = w >> 1;
  const int dkb = (w & 1) * 4;
  const int ot  = w - 4;
  const int st  = t >> 5, sdk = (t & 31) * 4;
  const size_t bt0 = (size_t)b*SEQ + tokbase;
  const int mytile = (w < 4) ? w : (w - 4);

  f32x4 S[4], T[4];
  #pragma unroll
  for (int tt=0;tt<4;tt++)
    #pragma unroll
    for (int r=0;r<4;r++){
      S[tt][r] = 0.f;
      T[tt][r] = (ismrg && ((dkb+tt)*16 + hk*4 + r) == (half*64 + dt*16 + lr)) ? 1.f : 0.f;
    }

  // -------- prologue --------
  uint2 kreg = *(const uint2*)(qkv + (bt0+st)*CONVD + 2048 + nk*128 + sdk);
  bf16x8 qf[4];
  if (w >= 4){
    const ushort_t* qrow = qkv + (bt0+lr)*CONVD + nk*128 + hk*8;
    #pragma unroll
    for (int ks=0;ks<4;ks++) qf[ks] = *(const bf16x8*)(qrow + ks*32);
  }
  ushort_t vreg[4] = {0,0,0,0};
  if (w < 4){
    #pragma unroll
    for (int r=0;r<4;r++)
      vreg[r] = qkv[(bt0+hk*4+r)*CONVD + 4096 + nv*128 + half*64 + w*16 + lr];
  }
  {
    float2 gb = make_float2(0.f,0.f);
    if (w==1 && lane<16) gb = egb[(bt0+lane)*NV_ + nv];
    *(uint2*)&Kl[st*136 + sdk] = kreg;
    if (w==1 && lane<16){
      float c = gb.x;
      #pragma unroll
      for (int o=1;o<16;o<<=1){ float tv = __shfl_up(c, o, 16); if (lane >= o) c += tv; }
      clB[lane] = c; blB[lane] = gb.y; eclB[lane] = __expf(c);
      float c15 = __shfl(c, 15, 16);
      kslB[lane] = __expf(c15 - c);
      if (lane==0) c15B[0] = c15;
    }
  }
  __syncthreads();

  int pb = 0;
  for (int base = 0; base < ntok; base += CCH){
    const int nbase = (base + CCH < ntok) ? base + CCH : base;
    const int pb16 = pb*16;

    // ================= phase 1: products + A/W/u/KT builds =================
    bf16x8 kf[4];
    if (w <= 4){
      #pragma unroll
      for (int ks=0;ks<4;ks++) kf[ks] = *(const bf16x8*)&Kl[lr*136 + hk*8 + ks*32];
    }
    f32x4 ph = (f32x4){0.f,0.f,0.f,0.f}, pl = ph, phA = ph, plA = ph;
    __builtin_amdgcn_s_setprio(1);
    #pragma unroll
    for (int ks=0;ks<4;ks++){
      bf16x8 xf = (w < 4) ? kf[ks] : qf[ks];
      bf16x8 yh = *(const bf16x8*)&S0h[(mytile*16+lr)*136 + hk*8 + ks*32];
      bf16x8 yl = *(const bf16x8*)&S0l[(mytile*16+lr)*136 + hk*8 + ks*32];
      ph = __builtin_amdgcn_mfma_f32_16x16x32_bf16(xf, yh, ph, 0,0,0);
      pl = __builtin_amdgcn_mfma_f32_16x16x32_bf16(xf, yl, pl, 0,0,0);
    }
    if (ismrg){
      #pragma unroll
      for (int ks=0;ks<4;ks++){
        bf16x8 xf = (w < 4) ? kf[ks] : qf[ks];
        bf16x8 yh = *(const bf16x8*)&T0h[(mytile*16+lr)*136 + hk*8 + ks*32];
        bf16x8 yl = *(const bf16x8*)&T0l[(mytile*16+lr)*136 + hk*8 + ks*32];
        phA = __builtin_amdgcn_mfma_f32_16x16x32_bf16(xf, yh, phA, 0,0,0);
        plA = __builtin_amdgcn_mfma_f32_16x16x32_bf16(xf, yl, plA, 0,0,0);
      }
    }
    __builtin_amdgcn_s_setprio(0);
    if (w == 1){ // A build
      f32x4 a = (f32x4){0.f,0.f,0.f,0.f};
      #pragma unroll
      for (int ks=0;ks<4;ks++) a = __builtin_amdgcn_mfma_f32_16x16x32_bf16(kf[ks], kf[ks], a, 0,0,0);
      #pragma unroll
      for (int r=0;r<4;r++){
        int i = hk*4 + r, j = lr;
        Al[i*20 + j] = (j < i) ? blB[pb16+i]*__expf(clB[pb16+i]-clB[pb16+j])*a[r] : 0.f;
      }
    }
    if (w == 4){ // W build
      f32x4 a = (f32x4){0.f,0.f,0.f,0.f};
      #pragma unroll
      for (int ks=0;ks<4;ks++) a = __builtin_amdgcn_mfma_f32_16x16x32_bf16(qf[ks], kf[ks], a, 0,0,0);
      #pragma unroll
      for (int r=0;r<4;r++){
        int i = hk*4 + r, j = lr;
        float val = (j <= i) ? __expf(clB[pb16+i]-clB[pb16+j])*a[r] : 0.f;
        Wl[i*40 + j] = f2bf(val);
      }
    }
    if (w < 4){ // u builds (real; aug has v=0)
      float4 uu;
      #pragma unroll
      for (int r=0;r<4;r++){
        int i = hk*4 + r;
        ((float*)&uu)[r] = blB[pb16+i]*(bf2f(vreg[r]) - eclB[pb16+i]*(ph[r] + pl[r]));
      }
      *(float4*)&Ul[(w*16 + lr)*20 + hk*4] = uu;
      if (ismrg){
        float4 ua;
        #pragma unroll
        for (int r=0;r<4;r++){
          int i = hk*4 + r;
          ((float*)&ua)[r] = -blB[pb16+i]*eclB[pb16+i]*(phA[r] + plA[r]);
        }
        *(float4*)&Ul[(64 + w*16 + lr)*20 + hk*4] = ua;
      }
    }
    if (w == 2 || w == 3){ // K'^T build
      int dk = t & 127;
      #pragma unroll
      for (int j=0;j<16;j+=2){
        unsigned p0 = f2bf(kslB[pb16+j]  * bf2f(Kl[j*136     + dk]));
        unsigned p1 = f2bf(kslB[pb16+j+1]* bf2f(Kl[(j+1)*136 + dk]));
        *(unsigned*)&KT[dk*40 + j] = p0 | (p1 << 16);
      }
    }
    __syncthreads();   // B3

    // ================= phase 2: substitutions (w0 real, w1 aug) || prefetch (others) =================
    kreg = *(const uint2*)(qkv + (bt0+nbase+st)*CONVD + 2048 + nk*128 + sdk);
    if (w >= 4){
      const ushort_t* qrow = qkv + (bt0 + nbase + lr)*CONVD + nk*128 + hk*8;
      #pragma unroll
      for (int ks=0;ks<4;ks++) qf[ks] = *(const bf16x8*)(qrow + ks*32);
    }
    if (w < 4){
      #pragma unroll
      for (int r=0;r<4;r++)
        vreg[r] = qkv[(bt0+nbase+hk*4+r)*CONVD + 4096 + nv*128 + half*64 + w*16 + lr];
    }
    float2 ebn = make_float2(0.f,0.f);
    if (w==1 && lane<16) ebn = egb[(bt0+nbase+lane)*NV_ + nv];
    bf16x8 yf[4];
    #pragma unroll
    for (int tt=0;tt<4;tt++) yf[tt] = *(const bf16x8*)&KT[((dkb+tt)*16+lr)*40 + hk*8];
    bf16x8 wfr;
    if (w >= 4) wfr = *(const bf16x8*)&Wl[lr*40 + hk*8];

    auto fsub = [&](int rowoff){
      float d[16];
      #pragma unroll
      for (int q=0;q<4;q++){
        float4 dd = *(const float4*)&Ul[(rowoff+lane)*20 + q*4];
        d[4*q]=dd.x; d[4*q+1]=dd.y; d[4*q+2]=dd.z; d[4*q+3]=dd.w;
      }
      #pragma unroll
      for (int rb=0;rb<4;rb++){
        float p0=0.f,p1=0.f,p2=0.f,p3=0.f;
        #pragma unroll
        for (int jb=0;jb<rb;jb++){
          float4 A0 = *(const float4*)&Al[(rb*4+0)*20 + jb*4];
          float4 A1 = *(const float4*)&Al[(rb*4+1)*20 + jb*4];
          float4 A2 = *(const float4*)&Al[(rb*4+2)*20 + jb*4];
          float4 A3 = *(const float4*)&Al[(rb*4+3)*20 + jb*4];
          p0 += A0.x*d[jb*4]+A0.y*d[jb*4+1]+A0.z*d[jb*4+2]+A0.w*d[jb*4+3];
          p1 += A1.x*d[jb*4]+A1.y*d[jb*4+1]+A1.z*d[jb*4+2]+A1.w*d[jb*4+3];
          p2 += A2.x*d[jb*4]+A2.y*d[jb*4+1]+A2.z*d[jb*4+2]+A2.w*d[jb*4+3];
          p3 += A3.x*d[jb*4]+A3.y*d[jb*4+1]+A3.z*d[jb*4+2]+A3.w*d[jb*4+3];
        }
        const int r0 = rb*4;
        d[r0+0] -= p0;
        d[r0+1] -= p1 + Al[(r0+1)*20+r0]*d[r0];
        d[r0+2] -= p2 + Al[(r0+2)*20+r0]*d[r0] + Al[(r0+2)*20+r0+1]*d[r0+1];
        d[r0+3] -= p3 + Al[(r0+3)*20+r0]*d[r0] + Al[(r0+3)*20+r0+1]*d[r0+1] + Al[(r0+3)*20+r0+2]*d[r0+2];
      }
      unsigned dd[8];
      #pragma unroll
      for (int p=0;p<8;p++) dd[p] = (unsigned)f2bf(d[2*p]) | ((unsigned)f2bf(d[2*p+1]) << 16);
      *(uint4*)&DT[(rowoff+lane)*40 + 0] = make_uint4(dd[0],dd[1],dd[2],dd[3]);
      *(uint4*)&DT[(rowoff+lane)*40 + 8] = make_uint4(dd[4],dd[5],dd[6],dd[7]);
    };
    if (w == 0){ __builtin_amdgcn_s_setprio(1); fsub(0);  __builtin_amdgcn_s_setprio(0); }
    if (ismrg && w == 1){ __builtin_amdgcn_s_setprio(1); fsub(64); __builtin_amdgcn_s_setprio(0); }
    __syncthreads();   // B4

    // ================= phase 3: O + state updates + writebacks + next staging =================
    if (w >= 4){
      bf16x8 dfr = *(const bf16x8*)&DT[(ot*16+lr)*40 + hk*8];
      f32x4 oo = __builtin_amdgcn_mfma_f32_16x16x32_bf16(wfr, dfr, (f32x4){0.f,0.f,0.f,0.f}, 0,0,0);
      #pragma unroll
      for (int r=0;r<4;r++){
        int i = hk*4 + r;
        outc[((bt0+base+i)*NV_ + nv)*(size_t)DV_ + half*64 + ot*16 + lr] = oo[r] + eclB[pb16+i]*(ph[r] + pl[r]);
      }
      if (ismrg){
        bf16x8 dfr2 = *(const bf16x8*)&DT[(64 + ot*16+lr)*40 + hk*8];
        f32x4 oo2 = __builtin_amdgcn_mfma_f32_16x16x32_bf16(wfr, dfr2, (f32x4){0.f,0.f,0.f,0.f}, 0,0,0);
        #pragma unroll
        for (int r=0;r<4;r++){
          int i = hk*4 + r;
          oaug[(((size_t)(b*NV_+nv))*HTOK2 + base + i)*128 + half*64 + ot*16 + lr]
            = f2bf(oo2[r] + eclB[pb16+i]*(phA[r] + plA[r]));
        }
      }
    }
    {
      float g15 = __expf(c15B[pb]);
      bf16x8 dB = *(const bf16x8*)&DT[(dt*16+lr)*40 + hk*8];
      __builtin_amdgcn_s_setprio(1);
      #pragma unroll
      for (int tt=0;tt<4;tt++){
        f32x4 s = S[tt];
        s[0]*=g15; s[1]*=g15; s[2]*=g15; s[3]*=g15;
        S[tt] = __builtin_amdgcn_mfma_f32_16x16x32_bf16(yf[tt], dB, s, 0,0,0);
      }
      if (ismrg){
        bf16x8 dB2 = *(const bf16x8*)&DT[(64 + dt*16+lr)*40 + hk*8];
        #pragma unroll
        for (int tt=0;tt<4;tt++){
          f32x4 s = T[tt];
          s[0]*=g15; s[1]*=g15; s[2]*=g15; s[3]*=g15;
          T[tt] = __builtin_amdgcn_mfma_f32_16x16x32_bf16(yf[tt], dB2, s, 0,0,0);
        }
      }
      __builtin_amdgcn_s_setprio(0);
    }
    {
      const int dv = dt*16 + lr;
      #pragma unroll
      for (int tt=0;tt<4;tt++){
        const int dk0 = (dkb+tt)*16 + hk*4;
        {
          float s0=S[tt][0], s1=S[tt][1], s2=S[tt][2], s3=S[tt][3];
          ushort_t h0=f2bf(s0), h1=f2bf(s1), h2=f2bf(s2), h3=f2bf(s3);
          *(uint2*)&S0h[dv*136 + dk0] = make_uint2((unsigned)h0 | ((unsigned)h1<<16),
                                                   (unsigned)h2 | ((unsigned)h3<<16));
          *(uint2*)&S0l[dv*136 + dk0] = make_uint2((unsigned)f2bf(s0-bf2f(h0)) | ((unsigned)f2bf(s1-bf2f(h1))<<16),
                                                   (unsigned)f2bf(s2-bf2f(h2)) | ((unsigned)f2bf(s3-bf2f(h3))<<16));
        }
        if (ismrg){
          float s0=T[tt][0], s1=T[tt][1], s2=T[tt][2], s3=T[tt][3];
          ushort_t h0=f2bf(s0), h1=f2bf(s1), h2=f2bf(s2), h3=f2bf(s3);
          *(uint2*)&T0h[dv*136 + dk0] = make_uint2((unsigned)h0 | ((unsigned)h1<<16),
                                                   (unsigned)h2 | ((unsigned)h3<<16));
          *(uint2*)&T0l[dv*136 + dk0] = make_uint2((unsigned)f2bf(s0-bf2f(h0)) | ((unsigned)f2bf(s1-bf2f(h1))<<16),
                                                   (unsigned)f2bf(s2-bf2f(h2)) | ((unsigned)f2bf(s3-bf2f(h3))<<16));
        }
      }
    }
    *(uint2*)&Kl[st*136 + sdk] = kreg;
    if (w==1 && lane<16){
      float c = ebn.x;
      #pragma unroll
      for (int o=1;o<16;o<<=1){ float tv = __shfl_up(c, o, 16); if (lane >= o) c += tv; }
      int q16 = (pb^1)*16;
      clB[q16+lane] = c; blB[q16+lane] = ebn.y; eclB[q16+lane] = __expf(c);
      float c15 = __shfl(c, 15, 16);
      kslB[q16+lane] = __expf(c15 - c);
      if (lane==0) c15B[pb^1] = c15;
    }
    __syncthreads();   // B5
    pb ^= 1;
  }

  if (wsf){
    for (int i = t; i < 64*128; i += 512){
      int dvl = i >> 7, dk = i & 127;
      size_t row = ((size_t)(b*NV_+nv)*128 + half*64 + dvl)*256;
      Sfin[row + dk]       = S0h[dvl*136 + dk];
      Sfin[row + 128 + dk] = S0l[dvl*136 + dk];
    }
  }
}

// ---------------- correction: core[tokens T0TOK..SEQ) += oaug @ Sfin^T (per head) ----------------
__global__ __launch_bounds__(256) void corr_gemm(const ushort_t* __restrict__ oaug, const ushort_t* __restrict__ Sfin,
                                                 float* __restrict__ core){
  __shared__ ushort_t As[128][32];
  __shared__ ushort_t Bs[128][32];
  const int head = blockIdx.y;
  const int m0 = blockIdx.x * 128;
  const int b = head >> 5, nv = head & 31;
  const int t = threadIdx.x, lane = t & 63, w = t >> 6;
  const int wm = w >> 1, wn = w & 1;
  const int srow = lane >> 2, scol = (lane & 3) * 8;
  const ushort_t* Abase = oaug + (size_t)head*HTOK2*128;
  const ushort_t* Bbase = Sfin + (size_t)head*128*256;
  ushort_t* lA0 = &As[     w*16][0];
  ushort_t* lA1 = &As[64 + w*16][0];
  ushort_t* lB0 = &Bs[     w*16][0];
  ushort_t* lB1 = &Bs[64 + w*16][0];
  f32x4 acc[4][4];
  #pragma unroll
  for (int i=0;i<4;i++)
    #pragma unroll
    for (int j=0;j<4;j++) acc[i][j] = (f32x4){0.f,0.f,0.f,0.f};
  const int lr = lane & 15, lk = (lane >> 4) * 8;
  for (int k0 = 0; k0 < 256; k0 += 32){
    const int ka = k0 & 127;
    int ra0 = m0 +      w*16 + srow; if (ra0 >= HTOK2) ra0 = HTOK2 - 1;
    int ra1 = m0 + 64 + w*16 + srow; if (ra1 >= HTOK2) ra1 = HTOK2 - 1;
    __builtin_amdgcn_global_load_lds((const __attribute__((address_space(1))) void*)(Abase + (size_t)ra0*128 + ka + scol),
                                     (__attribute__((address_space(3))) void*)lA0, 16, 0, 0);
    __builtin_amdgcn_global_load_lds((const __attribute__((address_space(1))) void*)(Abase + (size_t)ra1*128 + ka + scol),
                                     (__attribute__((address_space(3))) void*)lA1, 16, 0, 0);
    __builtin_amdgcn_global_load_lds((const __attribute__((address_space(1))) void*)(Bbase + (size_t)(     w*16 + srow)*256 + k0 + scol),
                                     (__attribute__((address_space(3))) void*)lB0, 16, 0, 0);
    __builtin_amdgcn_global_load_lds((const __attribute__((address_space(1))) void*)(Bbase + (size_t)(64 + w*16 + srow)*256 + k0 + scol),
                                     (__attribute__((address_space(3))) void*)lB1, 16, 0, 0);
    __syncthreads();
    bf16x8 af[4], bfv[4];
    #pragma unroll
    for (int i=0;i<4;i++) af[i]  = *(const bf16x8*)&As[wm*64 + i*16 + lr][lk];
    #pragma unroll
    for (int j=0;j<4;j++) bfv[j] = *(const bf16x8*)&Bs[wn*64 + j*16 + lr][lk];
    #pragma unroll
    for (int i=0;i<4;i++)
      #pragma unroll
      for (int j=0;j<4;j++)
        acc[i][j] = __builtin_amdgcn_mfma_f32_16x16x32_bf16(af[i], bfv[j], acc[i][j], 0, 0, 0);
    __syncthreads();
  }
  const int lg = lane >> 4;
  #pragma unroll
  for (int i=0;i<4;i++)
    #pragma unroll
    for (int j=0;j<4;j++)
      #pragma unroll
      for (int r=0;r<4;r++){
        int m = m0 + wm*64 + i*16 + lg*4 + r;
        int n = wn*64 + j*16 + lr;
        if (m < HTOK2){
          float* p = &core[(((size_t)b*SEQ + T0TOK + m)*NV_ + nv)*(size_t)DV_ + n];
          *p += acc[i][j][r];
        }
      }
}

// ---------------- gated RMSNorm -> bf16 ----------------
__global__ __launch_bounds__(128) void gatenorm_kernel(const float* __restrict__ outc, const ushort_t* __restrict__ qkvz,
                                                       const float* __restrict__ norm_w, ushort_t* __restrict__ gated){
  __shared__ float red[2];
  const int blk = blockIdx.x;
  const int nv = blk & 31;
  const size_t bt = (size_t)(blk >> 5);
  const int dv = threadIdx.x;
  float xv = outc[(bt*NV_ + nv)*(size_t)DV_ + dv];
  float ss = xv*xv;
  #pragma unroll
  for (int o=1;o<64;o<<=1) ss += __shfl_xor(ss, o);
  if ((threadIdx.x & 63)==0) red[threadIdx.x>>6] = ss;
  __syncthreads();
  float tot = red[0]+red[1];
  float xn = xv * rsqrtf(tot*(1.f/128.f) + 1e-6f) * norm_w[dv];
  int nk = nv>>1, r = nv&1;
  float z = bf2f(qkvz[bt*NQKVZ + nk*768 + 512 + r*128 + dv]);
  gated[bt*(size_t)4096 + nv*128 + dv] = f2bf(siluf_(z)*xn);
}

extern "C" void kernel_launch(void* const* d_in, const int* in_sizes, int n_in,
                              void* d_out, int out_size, void* d_ws, size_t ws_size,
                              hipStream_t stream){
  (void)in_sizes; (void)n_in; (void)out_size;
  const float* x      = (const float*)d_in[0];
  const float* W_qkvz = (const float*)d_in[1];
  const float* W_ba   = (const float*)d_in[2];
  const float* conv_w = (const float*)d_in[3];
  const float* dt_bias= (const float*)d_in[4];
  const float* A_log  = (const float*)d_in[5];
  const float* norm_w = (const float*)d_in[6];
  const float* W_out  = (const float*)d_in[7];
  float* outp = (float*)d_out;

  char* w = (char*)d_ws;
  const size_t R0 = 0;
  const size_t R1 = 100663296;
  const size_t R2 = R1 + 67108864;
  const size_t R3 = R2 + 67108864;
  const size_t R4 = R3 + 2097152;
  const size_t NEED_SP = R4 + 16777216 + 4194304;
  ushort_t* qkvz_bf = (ushort_t*)(w + R0);
  ushort_t* xb      = (ushort_t*)(w + R1);
  ushort_t* wqt     = (ushort_t*)(w + R1 + 16777216);
  ushort_t* qkv_bf  = (ushort_t*)(w + R1);
  ushort_t* gated   = (ushort_t*)(w + R1);
  float*    core    = (float*)   (w + R2);
  ushort_t* wot     = (ushort_t*)(w + R2);
  float*    ba      = (float*)   (w + R3);
  float2*   egb     = (float2*)  (w + R3 + 1048576);
  ushort_t* oaug    = (ushort_t*)(w + R4);
  ushort_t* Sfin    = (ushort_t*)(w + R4 + 16777216);

  hipError_t e1 = hipFuncSetAttribute((const void*)gemm_big<1>, hipFuncAttributeMaxDynamicSharedMemorySize, 98304);
  hipError_t e2 = hipFuncSetAttribute((const void*)gemm_big2<0>, hipFuncAttributeMaxDynamicSharedMemorySize, 73728);
  hipError_t e3 = hipFuncSetAttribute((const void*)recurrence_chunked, hipFuncAttributeMaxDynamicSharedMemorySize, RLDSZ);
  (void)e1; (void)e2;
  const bool seqpar = (ws_size >= NEED_SP) && (e3 == hipSuccess);

  cast_x_kernel<<<(MTOT*HID/4 + 255)/256, 256, 0, stream>>>(x, xb, MTOT*HID/4);
  transpose_cast<<<dim3(NQKVZ/64, HID/64), 256, 0, stream>>>(W_qkvz, wqt, HID, NQKVZ);
  gemm_big<1><<<dim3(NQKVZ/256, MTOT/256), 512, 98304, stream>>>(xb, wqt, (void*)qkvz_bf, MTOT, NQKVZ, HID);
  gemm_ba<<<MTOT/4, 256, 0, stream>>>(x, W_ba, ba);
  gbeta_kernel<<<(MTOT*NV_+255)/256, 256, 0, stream>>>(ba, A_log, dt_bias, egb);
  conv_norm_kernel<<<(MTOT/CT)*16, 256, 0, stream>>>(qkvz_bf, conv_w, qkv_bf);
  if (seqpar){
    recurrence_chunked<<<256, 512, RLDSZ, stream>>>(qkv_bf, egb, core, oaug, Sfin, 1);
    corr_gemm<<<dim3((HTOK2 + 127)/128, 64), 256, 0, stream>>>(oaug, Sfin, core);
  } else {
    recurrence_chunked<<<128, 512, RLDSZ, stream>>>(qkv_bf, egb, core, oaug, Sfin, 0);
  }
  gatenorm_kernel<<<MTOT*NV_, 128, 0, stream>>>(core, qkvz_bf, norm_w, gated);
  transpose_cast<<<dim3(2048/64, 4096/64), 256, 0, stream>>>(W_out, wot, 4096, 2048);
  gemm_big2<0><<<dim3(2048/128, MTOT/256), 512, 73728, stream>>>(gated, wot, (void*)outp, MTOT, 2048, 4096);
}

// Round 24
// 846.506 us; speedup vs baseline: 1.8819x; 1.0040x over previous
//
#include <hip/hip_runtime.h>
#include <stdint.h>

#define B_    2
#define SEQ   2048
#define HID   2048
#define NK_   16
#define NV_   32
#define DK_   128
#define DV_   128
#define NQKVZ 12288
#define CONVD 8192
#define MTOT  (B_*SEQ)   // 4096
#define CCH   16         // recurrence sub-chunk length
#define T0TOK 1216       // partition 0 length (76 chunks, single chain)
#define HTOK2 832        // partition 1 length (52 chunks, merged dual chain)
#define CT    8          // conv rolling tile
#define RLDSZ 110592     // recurrence dynamic LDS

typedef unsigned short ushort_t;
typedef __bf16 bf16x8 __attribute__((ext_vector_type(8)));
typedef float  f32x4  __attribute__((ext_vector_type(4)));
typedef unsigned short us4 __attribute__((ext_vector_type(4)));

__device__ __forceinline__ ushort_t f2bf(float f){
  union { float f; unsigned u; } v; v.f = f;
  unsigned r = v.u + 0x7FFFu + ((v.u >> 16) & 1u);
  return (ushort_t)(r >> 16);
}
__device__ __forceinline__ float bf2f(ushort_t u){
  union { unsigned u; float f; } v; v.u = ((unsigned)u) << 16; return v.f;
}
__device__ __forceinline__ float sigmoidf_(float x){ return 1.f/(1.f+__expf(-x)); }
__device__ __forceinline__ float siluf_(float x){ return x*sigmoidf_(x); }

// ---------------- cast x -> bf16 ----------------
__global__ void cast_x_kernel(const float* __restrict__ x, ushort_t* __restrict__ xb, int n4){
  int i = blockIdx.x*256 + threadIdx.x;
  if (i >= n4) return;
  float4 v = ((const float4*)x)[i];
  us4 o; o[0]=f2bf(v.x); o[1]=f2bf(v.y); o[2]=f2bf(v.z); o[3]=f2bf(v.w);
  ((us4*)xb)[i] = o;
}

// ---------------- transpose + cast W[K][N] -> Wt[N][K] bf16 ----------------
__global__ __launch_bounds__(256) void transpose_cast(const float* __restrict__ W, ushort_t* __restrict__ Wt,
                                                      int K, int N){
  __shared__ float tile[64][65];
  int n0 = blockIdx.x*64, k0 = blockIdx.y*64;
  int tx = threadIdx.x & 63, ty = threadIdx.x >> 6;
  #pragma unroll
  for (int i=0;i<16;i++){
    int kr = ty + i*4;
    tile[kr][tx] = W[(size_t)(k0+kr)*N + n0+tx];
  }
  __syncthreads();
  #pragma unroll
  for (int i=0;i<16;i++){
    int nr = ty + i*4;
    Wt[(size_t)(n0+nr)*K + k0+tx] = f2bf(tile[tx][nr]);
  }
}

// ---------------- big-tile GEMM: 256x256, BK=32, 4-deep pipeline, counted vmcnt ----------------
template<int OUTBF>
__global__ __launch_bounds__(512, 2) void gemm_big(const ushort_t* __restrict__ A, const ushort_t* __restrict__ Bt,
                                                   void* __restrict__ Cv, int M, int N, int K){
  extern __shared__ ushort_t dynlds[];
  ushort_t* SA = dynlds;              // 4 * 8192 elems (16KB each)
  ushort_t* SB = dynlds + 4*8192;
  const int t = threadIdx.x;
  const int lane = t & 63, w = t >> 6;
  const int wm = w >> 2, wn = w & 3;
  const int lr = lane & 15, hk = lane >> 4;
  const int gx = gridDim.x;
  const int nwg = gx * gridDim.y;
  const int flat = blockIdx.y*gx + blockIdx.x;
  const int cpx = nwg >> 3;
  const int swzb = (flat & 7)*cpx + (flat >> 3);
  const int m0 = (swzb / gx) * 256, n0 = (swzb % gx) * 256;

  int srow[2], scol[2];
  #pragma unroll
  for (int q=0;q<2;q++){
    int p  = (w*2+q)*1024 + lane*16;
    int lg = p ^ (((p>>9)&1)<<5);
    srow[q] = lg >> 6;
    scol[q] = (lg & 63) >> 1;
  }
  int phA[8], phB[4];
  #pragma unroll
  for (int mi=0;mi<8;mi++){
    int lg = (wm*128 + mi*16 + lr)*64 + hk*16;
    phA[mi] = lg ^ (((lg>>9)&1)<<5);
  }
  #pragma unroll
  for (int ni=0;ni<4;ni++){
    int lg = (wn*64 + ni*16 + lr)*64 + hk*16;
    phB[ni] = lg ^ (((lg>>9)&1)<<5);
  }

  auto stage = [&](int j, int bufb){
    #pragma unroll
    for (int q=0;q<2;q++)
      __builtin_amdgcn_global_load_lds(
        (const __attribute__((address_space(1))) void*)(A + (size_t)(m0+srow[q])*K + j*32 + scol[q]),
        (__attribute__((address_space(3))) void*)(SA + bufb*8192 + (w*2+q)*512), 16, 0, 0);
    #pragma unroll
    for (int q=0;q<2;q++)
      __builtin_amdgcn_global_load_lds(
        (const __attribute__((address_space(1))) void*)(Bt + (size_t)(n0+srow[q])*K + j*32 + scol[q]),
        (__attribute__((address_space(3))) void*)(SB + bufb*8192 + (w*2+q)*512), 16, 0, 0);
  };

  f32x4 acc[8][4];
  #pragma unroll
  for (int mi=0;mi<8;mi++)
    #pragma unroll
    for (int ni=0;ni<4;ni++) acc[mi][ni] = (f32x4){0.f,0.f,0.f,0.f};

  const int NT = K >> 5;
  stage(0, 0);
  stage(1, 1);
  stage(2, 2);
  asm volatile("s_waitcnt vmcnt(8)" ::: "memory");   // tile 0 landed; tiles 1,2 in flight
  __builtin_amdgcn_s_barrier();
  __builtin_amdgcn_sched_barrier(0);

  int cur = 0;
  for (int j = 0; j < NT; ++j){
    int nb = cur + 3; if (nb >= 4) nb -= 4;
    if (j + 3 < NT) stage(j+3, nb);                  // into buffer freed at end of iter j-1
    const char* bA = (const char*)(SA + cur*8192);
    const char* bB = (const char*)(SB + cur*8192);
    bf16x8 af[8], bfv[4];
    #pragma unroll
    for (int mi=0;mi<8;mi++) af[mi]  = *(const bf16x8*)(bA + phA[mi]);
    #pragma unroll
    for (int ni=0;ni<4;ni++) bfv[ni] = *(const bf16x8*)(bB + phB[ni]);
    #pragma unroll
    for (int mi=0;mi<8;mi++)
      #pragma unroll
      for (int ni=0;ni<4;ni++)
        acc[mi][ni] = __builtin_amdgcn_mfma_f32_16x16x32_bf16(af[mi], bfv[ni], acc[mi][ni], 0, 0, 0);
    if (j + 1 < NT){
      if (j + 3 < NT)      asm volatile("s_waitcnt vmcnt(8)" ::: "memory");  // j+2,j+3 stay in flight
      else if (j + 2 < NT) asm volatile("s_waitcnt vmcnt(4)" ::: "memory");  // j+2 stays in flight
      else                 asm volatile("s_waitcnt vmcnt(0)" ::: "memory");  // tail drain
      __builtin_amdgcn_s_barrier();
      __builtin_amdgcn_sched_barrier(0);
    }
    cur = cur + 1; if (cur >= 4) cur -= 4;
  }

  #pragma unroll
  for (int mi=0;mi<8;mi++)
    #pragma unroll
    for (int ni=0;ni<4;ni++)
      #pragma unroll
      for (int r=0;r<4;r++){
        int m = m0 + wm*128 + mi*16 + hk*4 + r;
        int n = n0 + wn*64  + ni*16 + lr;
        if (OUTBF) ((ushort_t*)Cv)[(size_t)m*N + n] = f2bf(acc[mi][ni][r]);
        else       ((float*)Cv)[(size_t)m*N + n]    = acc[mi][ni][r];
      }
}

// ---------------- big-tile GEMM variant: 256M x 128N, 4-deep ----------------
template<int OUTBF>
__global__ __launch_bounds__(512, 2) void gemm_big2(const ushort_t* __restrict__ A, const ushort_t* __restrict__ Bt,
                                                    void* __restrict__ Cv, int M, int N, int K){
  extern __shared__ ushort_t dynlds[];
  ushort_t* SA = dynlds;              // 4 * 8192 elems (16KB each)
  ushort_t* SB = dynlds + 4*8192;     // 4 * 4096 elems (8KB each)
  const int t = threadIdx.x;
  const int lane = t & 63, w = t >> 6;
  const int wm = w >> 1, wn = w & 1;
  const int lr = lane & 15, hk = lane >> 4;
  const int gx = gridDim.x;
  const int nwg = gx * gridDim.y;
  const int flat = blockIdx.y*gx + blockIdx.x;
  const int cpx = nwg >> 3;
  const int swzb = (flat & 7)*cpx + (flat >> 3);
  const int m0 = (swzb / gx) * 256, n0 = (swzb % gx) * 128;

  int srA[2], scA[2];
  #pragma unroll
  for (int q=0;q<2;q++){
    int p  = (w*2+q)*1024 + lane*16;
    int lg = p ^ (((p>>9)&1)<<5);
    srA[q] = lg >> 6;
    scA[q] = (lg & 63) >> 1;
  }
  int srB, scB;
  {
    int p  = w*1024 + lane*16;
    int lg = p ^ (((p>>9)&1)<<5);
    srB = lg >> 6;
    scB = (lg & 63) >> 1;
  }
  int phA[4], phB[4];
  #pragma unroll
  for (int mi=0;mi<4;mi++){
    int lg = (wm*64 + mi*16 + lr)*64 + hk*16;
    phA[mi] = lg ^ (((lg>>9)&1)<<5);
  }
  #pragma unroll
  for (int ni=0;ni<4;ni++){
    int lg = (wn*64 + ni*16 + lr)*64 + hk*16;
    phB[ni] = lg ^ (((lg>>9)&1)<<5);
  }

  auto stage = [&](int j, int bufb){
    #pragma unroll
    for (int q=0;q<2;q++)
      __builtin_amdgcn_global_load_lds(
        (const __attribute__((address_space(1))) void*)(A + (size_t)(m0+srA[q])*K + j*32 + scA[q]),
        (__attribute__((address_space(3))) void*)(SA + bufb*8192 + (w*2+q)*512), 16, 0, 0);
    __builtin_amdgcn_global_load_lds(
        (const __attribute__((address_space(1))) void*)(Bt + (size_t)(n0+srB)*K + j*32 + scB),
        (__attribute__((address_space(3))) void*)(SB + bufb*4096 + w*512), 16, 0, 0);
  };

  f32x4 acc[4][4];
  #pragma unroll
  for (int mi=0;mi<4;mi++)
    #pragma unroll
    for (int ni=0;ni<4;ni++) acc[mi][ni] = (f32x4){0.f,0.f,0.f,0.f};

  const int NT = K >> 5;
  stage(0, 0);
  stage(1, 1);
  stage(2, 2);
  asm volatile("s_waitcnt vmcnt(6)" ::: "memory");   // tile 0 landed; tiles 1,2 in flight
  __builtin_amdgcn_s_barrier();
  __builtin_amdgcn_sched_barrier(0);

  int cur = 0;
  for (int j = 0; j < NT; ++j){
    int nb = cur + 3; if (nb >= 4) nb -= 4;
    if (j + 3 < NT) stage(j+3, nb);
    const char* bA = (const char*)(SA + cur*8192);
    const char* bB = (const char*)(SB + cur*4096);
    bf16x8 af[4], bfv[4];
    #pragma unroll
    for (int mi=0;mi<4;mi++) af[mi]  = *(const bf16x8*)(bA + phA[mi]);
    #pragma unroll
    for (int ni=0;ni<4;ni++) bfv[ni] = *(const bf16x8*)(bB + phB[ni]);
    #pragma unroll
    for (int mi=0;mi<4;mi++)
      #pragma unroll
      for (int ni=0;ni<4;ni++)
        acc[mi][ni] = __builtin_amdgcn_mfma_f32_16x16x32_bf16(af[mi], bfv[ni], acc[mi][ni], 0, 0, 0);
    if (j + 1 < NT){
      if (j + 3 < NT)      asm volatile("s_waitcnt vmcnt(6)" ::: "memory");
      else if (j + 2 < NT) asm volatile("s_waitcnt vmcnt(3)" ::: "memory");
      else                 asm volatile("s_waitcnt vmcnt(0)" ::: "memory");
      __builtin_amdgcn_s_barrier();
      __builtin_amdgcn_sched_barrier(0);
    }
    cur = cur + 1; if (cur >= 4) cur -= 4;
  }

  #pragma unroll
  for (int mi=0;mi<4;mi++)
    #pragma unroll
    for (int ni=0;ni<4;ni++)
      #pragma unroll
      for (int r=0;r<4;r++){
        int m = m0 + wm*64 + mi*16 + hk*4 + r;
        int n = n0 + wn*64 + ni*16 + lr;
        if (OUTBF) ((ushort_t*)Cv)[(size_t)m*N + n] = f2bf(acc[mi][ni][r]);
        else       ((float*)Cv)[(size_t)m*N + n]    = acc[mi][ni][r];
      }
}

// ---------------- ba = x @ W_ba (fp32, N=64) ----------------
__global__ __launch_bounds__(256) void gemm_ba(const float* __restrict__ x, const float* __restrict__ Wba,
                                               float* __restrict__ ba){
  int lane = threadIdx.x & 63;
  int wid  = threadIdx.x >> 6;
  int row  = blockIdx.x*4 + wid;
  const float* xr = x + (size_t)row*HID;
  float acc = 0.f;
  for (int k=0;k<HID;k+=4){
    float4 xv = *(const float4*)&xr[k];
    acc += xv.x * Wba[(size_t)(k+0)*64 + lane];
    acc += xv.y * Wba[(size_t)(k+1)*64 + lane];
    acc += xv.z * Wba[(size_t)(k+2)*64 + lane];
    acc += xv.w * Wba[(size_t)(k+3)*64 + lane];
  }
  ba[(size_t)row*64 + lane] = acc;
}

// ---------------- conv(k=4) + SiLU + q/k RMS-norm (rolling window) ----------------
__global__ __launch_bounds__(256) void conv_norm_kernel(const ushort_t* __restrict__ qkvz, const float* __restrict__ conv_w,
                                                        ushort_t* __restrict__ qkv){
  const int blk = blockIdx.x;
  const int bt0 = (blk >> 4) * CT;
  const int ts0 = bt0 & (SEQ-1);
  const int gi = (blk & 15)*4 + (threadIdx.x >> 6);
  const int e2 = threadIdx.x & 63;
  const int dk = 2*e2;
  int col;
  if (gi < 16)       col = gi*768 + dk;
  else if (gi < 32)  col = (gi-16)*768 + 128 + dk;
  else { int nv = gi-32; col = (nv>>1)*768 + 256 + (nv&1)*128 + dk; }
  const int c = gi*128 + dk;
  const float4 w0 = *(const float4*)&conv_w[(size_t)c*4];
  const float4 w1 = *(const float4*)&conv_w[(size_t)(c+1)*4];
  ushort2 h0 = (ts0>=1) ? *(const ushort2*)&qkvz[(size_t)(bt0-3)*NQKVZ + col] : make_ushort2(0,0);
  ushort2 h1 = (ts0>=1) ? *(const ushort2*)&qkvz[(size_t)(bt0-2)*NQKVZ + col] : make_ushort2(0,0);
  ushort2 h2 = (ts0>=1) ? *(const ushort2*)&qkvz[(size_t)(bt0-1)*NQKVZ + col] : make_ushort2(0,0);
  const float scale = (gi < 16) ? (1.f/128.f) : 0.08838834764831845f;
  #pragma unroll
  for (int tt=0; tt<CT; ++tt){
    const int bt = bt0 + tt;
    ushort2 h3 = *(const ushort2*)&qkvz[(size_t)bt*NQKVZ + col];
    float y0 = siluf_(bf2f(h0.x)*w0.x + bf2f(h1.x)*w0.y + bf2f(h2.x)*w0.z + bf2f(h3.x)*w0.w);
    float y1 = siluf_(bf2f(h0.y)*w1.x + bf2f(h1.y)*w1.y + bf2f(h2.y)*w1.z + bf2f(h3.y)*w1.w);
    float o0 = y0, o1 = y1;
    if (gi < 32){
      float ss = y0*y0 + y1*y1;
      #pragma unroll
      for (int o=1;o<64;o<<=1) ss += __shfl_xor(ss, o);
      float rs = rsqrtf(ss*(1.f/128.f) + 1e-6f);
      o0 = y0*rs*scale; o1 = y1*rs*scale;
    }
    ushort2 ov; ov.x = f2bf(o0); ov.y = f2bf(o1);
    *(ushort2*)&qkv[(size_t)bt*CONVD + gi*128 + dk] = ov;
    h0 = h1; h1 = h2; h2 = h3;
  }
}

// ---------------- {g, beta} as float2 ----------------
__global__ void gbeta_kernel(const float* __restrict__ ba, const float* __restrict__ A_log,
                             const float* __restrict__ dt_bias, float2* __restrict__ egb){
  int idx = blockIdx.x*256 + threadIdx.x;
  if (idx >= MTOT*NV_) return;
  int nv = idx & 31;
  int bt = idx >> 5;
  int nk = nv >> 1, r = nv & 1;
  float bg = ba[(size_t)bt*64 + nk*4 + r];
  float ag = ba[(size_t)bt*64 + nk*4 + 2 + r];
  float ad = ag + dt_bias[nv];
  float sp = fmaxf(ad, 0.f) + log1pf(__expf(-fabsf(ad)));
  float g  = -__expf(A_log[nv]) * sp;
  egb[idx] = make_float2(g, sigmoidf_(bg));
}

// ---------------- chunked gated delta-rule, seq-parallel P=2 (asymmetric) with MERGED 2nd blocks ----------------
__global__ __launch_bounds__(512) void recurrence_chunked(const ushort_t* __restrict__ qkv,
                                                          const float2* __restrict__ egb,
                                                          float* __restrict__ outc,
                                                          ushort_t* __restrict__ oaug,
                                                          ushort_t* __restrict__ Sfin,
                                                          int pmode){
  extern __shared__ char rlds[];
  ushort_t* Kl  = (ushort_t*)(rlds + 0);       // 16*136
  ushort_t* S0h = (ushort_t*)(rlds + 4352);    // 64*136
  ushort_t* S0l = (ushort_t*)(rlds + 21760);
  ushort_t* T0h = (ushort_t*)(rlds + 39168);   // aug state
  ushort_t* T0l = (ushort_t*)(rlds + 56576);
  ushort_t* KT  = (ushort_t*)(rlds + 73984);   // 128*40
  ushort_t* DT  = (ushort_t*)(rlds + 84224);   // 128*40 (rows 0-63 real, 64-127 aug)
  ushort_t* Wl  = (ushort_t*)(rlds + 94464);   // 16*40
  float*    Al  = (float*)   (rlds + 95744);   // 16*20
  float*    Ul  = (float*)   (rlds + 97024);   // 128*20
  float*    clB = (float*)   (rlds + 107264);  // [2][16]
  float*    blB = clB + 32;
  float*    eclB= clB + 64;
  float*    kslB= clB + 96;
  float*    c15B= clB + 128;                   // [2]

  const int bi = blockIdx.x;
  int hb, tokbase, ntok;
  bool ismrg = false, wsf = false;
  if (pmode == 0){ hb = bi; tokbase = 0; ntok = SEQ; }
  else {
    if (bi < 128){ hb = bi; tokbase = 0; ntok = T0TOK; wsf = true; }
    else { hb = bi - 128; tokbase = T0TOK; ntok = HTOK2; ismrg = true; }
  }
  const int b    = hb >> 6;
  const int nv   = (hb >> 1) & 31;
  const int half = hb & 1;
  const int nk   = nv >> 1;
  const int t    = threadIdx.x;
  const int lane = t & 63, w = t >> 6;
  const int lr   = lane & 15, hk = lane >> 4;

  for (int i = t; i < 128*40; i += 512){ KT[i] = 0; DT[i] = 0; }
  for (int i = t; i < 16*40;  i += 512) Wl[i] = 0;
  for (int i = t; i < 64*136; i += 512){
    S0h[i] = 0; S0l[i] = 0;
    if (ismrg){ T0h[i] = 0; T0l[i] = 0; }
  }
  __syncthreads();
  if (ismrg && t < 64) T0h[t*136 + half*64 + t] = (ushort_t)0x3F80;  // bf16(1.0) identity

  const int dt  = w >> 1;
  const int dkb = (w & 1) * 4;
  const int ot  = w - 4;
  const int st  = t >> 5, sdk = (t & 31) * 4;
  const size_t bt0 = (size_t)b*SEQ + tokbase;
  const int mytile = (w < 4) ? w : (w - 4);

  f32x4 S[4], T[4];
  #pragma unroll
  for (int tt=0;tt<4;tt++)
    #pragma unroll
    for (int r=0;r<4;r++){
      S[tt][r] = 0.f;
      T[tt][r] = (ismrg && ((dkb+tt)*16 + hk*4 + r) == (half*64 + dt*16 + lr)) ? 1.f : 0.f;
    }

  // -------- prologue --------
  uint2 kreg = *(const uint2*)(qkv + (bt0+st)*CONVD + 2048 + nk*128 + sdk);
  bf16x8 qf[4];
  if (w >= 4){
    const ushort_t* qrow = qkv + (bt0+lr)*CONVD + nk*128 + hk*8;
    #pragma unroll
    for (int ks=0;ks<4;ks++) qf[ks] = *(const bf16x8*)(qrow + ks*32);
  }
  ushort_t vreg[4] = {0,0,0,0};
  if (w < 4){
    #pragma unroll
    for (int r=0;r<4;r++)
      vreg[r] = qkv[(bt0+hk*4+r)*CONVD + 4096 + nv*128 + half*64 + w*16 + lr];
  }
  {
    float2 gb = make_float2(0.f,0.f);
    if (w==1 && lane<16) gb = egb[(bt0+lane)*NV_ + nv];
    *(uint2*)&Kl[st*136 + sdk] = kreg;
    if (w==1 && lane<16){
      float c = gb.x;
      #pragma unroll
      for (int o=1;o<16;o<<=1){ float tv = __shfl_up(c, o, 16); if (lane >= o) c += tv; }
      clB[lane] = c; blB[lane] = gb.y; eclB[lane] = __expf(c);
      float c15 = __shfl(c, 15, 16);
      kslB[lane] = __expf(c15 - c);
      if (lane==0) c15B[0] = c15;
    }
  }
  __syncthreads();

  int pb = 0;
  for (int base = 0; base < ntok; base += CCH){
    const int nbase = (base + CCH < ntok) ? base + CCH : base;
    const int pb16 = pb*16;

    // ================= phase 1: products + A/W/u/KT builds =================
    bf16x8 kf[4];
    if (w <= 4){
      #pragma unroll
      for (int ks=0;ks<4;ks++) kf[ks] = *(const bf16x8*)&Kl[lr*136 + hk*8 + ks*32];
    }
    f32x4 ph = (f32x4){0.f,0.f,0.f,0.f}, pl = ph, phA = ph, plA = ph;
    __builtin_amdgcn_s_setprio(1);
    #pragma unroll
    for (int ks=0;ks<4;ks++){
      bf16x8 xf = (w < 4) ? kf[ks] : qf[ks];
      bf16x8 yh = *(const bf16x8*)&S0h[(mytile*16+lr)*136 + hk*8 + ks*32];
      bf16x8 yl = *(const bf16x8*)&S0l[(mytile*16+lr)*136 + hk*8 + ks*32];
      ph = __builtin_amdgcn_mfma_f32_16x16x32_bf16(xf, yh, ph, 0,0,0);
      pl = __builtin_amdgcn_mfma_f32_16x16x32_bf16(xf, yl, pl, 0,0,0);
    }
    if (ismrg){
      #pragma unroll
      for (int ks=0;ks<4;ks++){
        bf16x8 xf = (w < 4) ? kf[ks] : qf[ks];
        bf16x8 yh = *(const bf16x8*)&T0h[(mytile*16+lr)*136 + hk*8 + ks*32];
        bf16x8 yl = *(const bf16x8*)&T0l[(mytile*16+lr)*136 + hk*8 + ks*32];
        phA = __builtin_amdgcn_mfma_f32_16x16x32_bf16(xf, yh, phA, 0,0,0);
        plA = __builtin_amdgcn_mfma_f32_16x16x32_bf16(xf, yl, plA, 0,0,0);
      }
    }
    __builtin_amdgcn_s_setprio(0);
    if (w == 1){ // A build
      f32x4 a = (f32x4){0.f,0.f,0.f,0.f};
      #pragma unroll
      for (int ks=0;ks<4;ks++) a = __builtin_amdgcn_mfma_f32_16x16x32_bf16(kf[ks], kf[ks], a, 0,0,0);
      #pragma unroll
      for (int r=0;r<4;r++){
        int i = hk*4 + r, j = lr;
        Al[i*20 + j] = (j < i) ? blB[pb16+i]*__expf(clB[pb16+i]-clB[pb16+j])*a[r] : 0.f;
      }
    }
    if (w == 4){ // W build
      f32x4 a = (f32x4){0.f,0.f,0.f,0.f};
      #pragma unroll
      for (int ks=0;ks<4;ks++) a = __builtin_amdgcn_mfma_f32_16x16x32_bf16(qf[ks], kf[ks], a, 0,0,0);
      #pragma unroll
      for (int r=0;r<4;r++){
        int i = hk*4 + r, j = lr;
        float val = (j <= i) ? __expf(clB[pb16+i]-clB[pb16+j])*a[r] : 0.f;
        Wl[i*40 + j] = f2bf(val);
      }
    }
    if (w < 4){ // u builds (real; aug has v=0)
      float4 uu;
      #pragma unroll
      for (int r=0;r<4;r++){
        int i = hk*4 + r;
        ((float*)&uu)[r] = blB[pb16+i]*(bf2f(vreg[r]) - eclB[pb16+i]*(ph[r] + pl[r]));
      }
      *(float4*)&Ul[(w*16 + lr)*20 + hk*4] = uu;
      if (ismrg){
        float4 ua;
        #pragma unroll
        for (int r=0;r<4;r++){
          int i = hk*4 + r;
          ((float*)&ua)[r] = -blB[pb16+i]*eclB[pb16+i]*(phA[r] + plA[r]);
        }
        *(float4*)&Ul[(64 + w*16 + lr)*20 + hk*4] = ua;
      }
    }
    if (w == 2 || w == 3){ // K'^T build
      int dk = t & 127;
      #pragma unroll
      for (int j=0;j<16;j+=2){
        unsigned p0 = f2bf(kslB[pb16+j]  * bf2f(Kl[j*136     + dk]));
        unsigned p1 = f2bf(kslB[pb16+j+1]* bf2f(Kl[(j+1)*136 + dk]));
        *(unsigned*)&KT[dk*40 + j] = p0 | (p1 << 16);
      }
    }
    __syncthreads();   // B3

    // ================= phase 2: substitutions (w0 real, w1 aug) || prefetch (others) =================
    kreg = *(const uint2*)(qkv + (bt0+nbase+st)*CONVD + 2048 + nk*128 + sdk);
    if (w >= 4){
      const ushort_t* qrow = qkv + (bt0 + nbase + lr)*CONVD + nk*128 + hk*8;
      #pragma unroll
      for (int ks=0;ks<4;ks++) qf[ks] = *(const bf16x8*)(qrow + ks*32);
    }
    if (w < 4){
      #pragma unroll
      for (int r=0;r<4;r++)
        vreg[r] = qkv[(bt0+nbase+hk*4+r)*CONVD + 4096 + nv*128 + half*64 + w*16 + lr];
    }
    float2 ebn = make_float2(0.f,0.f);
    if (w==1 && lane<16) ebn = egb[(bt0+nbase+lane)*NV_ + nv];
    bf16x8 yf[4];
    #pragma unroll
    for (int tt=0;tt<4;tt++) yf[tt] = *(const bf16x8*)&KT[((dkb+tt)*16+lr)*40 + hk*8];
    bf16x8 wfr;
    if (w >= 4) wfr = *(const bf16x8*)&Wl[lr*40 + hk*8];

    auto fsub = [&](int rowoff){
      float d[16];
      #pragma unroll
      for (int q=0;q<4;q++){
        float4 dd = *(const float4*)&Ul[(rowoff+lane)*20 + q*4];
        d[4*q]=dd.x; d[4*q+1]=dd.y; d[4*q+2]=dd.z; d[4*q+3]=dd.w;
      }
      #pragma unroll
      for (int rb=0;rb<4;rb++){
        float p0=0.f,p1=0.f,p2=0.f,p3=0.f;
        #pragma unroll
        for (int jb=0;jb<rb;jb++){
          float4 A0 = *(const float4*)&Al[(rb*4+0)*20 + jb*4];
          float4 A1 = *(const float4*)&Al[(rb*4+1)*20 + jb*4];
          float4 A2 = *(const float4*)&Al[(rb*4+2)*20 + jb*4];
          float4 A3 = *(const float4*)&Al[(rb*4+3)*20 + jb*4];
          p0 += A0.x*d[jb*4]+A0.y*d[jb*4+1]+A0.z*d[jb*4+2]+A0.w*d[jb*4+3];
          p1 += A1.x*d[jb*4]+A1.y*d[jb*4+1]+A1.z*d[jb*4+2]+A1.w*d[jb*4+3];
          p2 += A2.x*d[jb*4]+A2.y*d[jb*4+1]+A2.z*d[jb*4+2]+A2.w*d[jb*4+3];
          p3 += A3.x*d[jb*4]+A3.y*d[jb*4+1]+A3.z*d[jb*4+2]+A3.w*d[jb*4+3];
        }
        const int r0 = rb*4;
        d[r0+0] -= p0;
        d[r0+1] -= p1 + Al[(r0+1)*20+r0]*d[r0];
        d[r0+2] -= p2 + Al[(r0+2)*20+r0]*d[r0] + Al[(r0+2)*20+r0+1]*d[r0+1];
        d[r0+3] -= p3 + Al[(r0+3)*20+r0]*d[r0] + Al[(r0+3)*20+r0+1]*d[r0+1] + Al[(r0+3)*20+r0+2]*d[r0+2];
      }
      unsigned dd[8];
      #pragma unroll
      for (int p=0;p<8;p++) dd[p] = (unsigned)f2bf(d[2*p]) | ((unsigned)f2bf(d[2*p+1]) << 16);
      *(uint4*)&DT[(rowoff+lane)*40 + 0] = make_uint4(dd[0],dd[1],dd[2],dd[3]);
      *(uint4*)&DT[(rowoff+lane)*40 + 8] = make_uint4(dd[4],dd[5],dd[6],dd[7]);
    };
    if (w == 0){ __builtin_amdgcn_s_setprio(1); fsub(0);  __builtin_amdgcn_s_setprio(0); }
    if (ismrg && w == 1){ __builtin_amdgcn_s_setprio(1); fsub(64); __builtin_amdgcn_s_setprio(0); }
    __syncthreads();   // B4

    // ================= phase 3: O + state updates + writebacks + next staging =================
    if (w >= 4){
      bf16x8 dfr = *(const bf16x8*)&DT[(ot*16+lr)*40 + hk*8];
      f32x4 oo = __builtin_amdgcn_mfma_f32_16x16x32_bf16(wfr, dfr, (f32x4){0.f,0.f,0.f,0.f}, 0,0,0);
      #pragma unroll
      for (int r=0;r<4;r++){
        int i = hk*4 + r;
        outc[((bt0+base+i)*NV_ + nv)*(size_t)DV_ + half*64 + ot*16 + lr] = oo[r] + eclB[pb16+i]*(ph[r] + pl[r]);
      }
      if (ismrg){
        bf16x8 dfr2 = *(const bf16x8*)&DT[(64 + ot*16+lr)*40 + hk*8];
        f32x4 oo2 = __builtin_amdgcn_mfma_f32_16x16x32_bf16(wfr, dfr2, (f32x4){0.f,0.f,0.f,0.f}, 0,0,0);
        #pragma unroll
        for (int r=0;r<4;r++){
          int i = hk*4 + r;
          oaug[(((size_t)(b*NV_+nv))*HTOK2 + base + i)*128 + half*64 + ot*16 + lr]
            = f2bf(oo2[r] + eclB[pb16+i]*(phA[r] + plA[r]));
        }
      }
    }
    {
      float g15 = __expf(c15B[pb]);
      bf16x8 dB = *(const bf16x8*)&DT[(dt*16+lr)*40 + hk*8];
      __builtin_amdgcn_s_setprio(1);
      #pragma unroll
      for (int tt=0;tt<4;tt++){
        f32x4 s = S[tt];
        s[0]*=g15; s[1]*=g15; s[2]*=g15; s[3]*=g15;
        S[tt] = __builtin_amdgcn_mfma_f32_16x16x32_bf16(yf[tt], dB, s, 0,0,0);
      }
      if (ismrg){
        bf16x8 dB2 = *(const bf16x8*)&DT[(64 + dt*16+lr)*40 + hk*8];
        #pragma unroll
        for (int tt=0;tt<4;tt++){
          f32x4 s = T[tt];
          s[0]*=g15; s[1]*=g15; s[2]*=g15; s[3]*=g15;
          T[tt] = __builtin_amdgcn_mfma_f32_16x16x32_bf16(yf[tt], dB2, s, 0,0,0);
        }
      }
      __builtin_amdgcn_s_setprio(0);
    }
    {
      const int dv = dt*16 + lr;
      #pragma unroll
      for (int tt=0;tt<4;tt++){
        const int dk0 = (dkb+tt)*16 + hk*4;
        {
          float s0=S[tt][0], s1=S[tt][1], s2=S[tt][2], s3=S[tt][3];
          ushort_t h0=f2bf(s0), h1=f2bf(s1), h2=f2bf(s2), h3=f2bf(s3);
          *(uint2*)&S0h[dv*136 + dk0] = make_uint2((unsigned)h0 | ((unsigned)h1<<16),
                                                   (unsigned)h2 | ((unsigned)h3<<16));
          *(uint2*)&S0l[dv*136 + dk0] = make_uint2((unsigned)f2bf(s0-bf2f(h0)) | ((unsigned)f2bf(s1-bf2f(h1))<<16),
                                                   (unsigned)f2bf(s2-bf2f(h2)) | ((unsigned)f2bf(s3-bf2f(h3))<<16));
        }
        if (ismrg){
          float s0=T[tt][0], s1=T[tt][1], s2=T[tt][2], s3=T[tt][3];
          ushort_t h0=f2bf(s0), h1=f2bf(s1), h2=f2bf(s2), h3=f2bf(s3);
          *(uint2*)&T0h[dv*136 + dk0] = make_uint2((unsigned)h0 | ((unsigned)h1<<16),
                                                   (unsigned)h2 | ((unsigned)h3<<16));
          *(uint2*)&T0l[dv*136 + dk0] = make_uint2((unsigned)f2bf(s0-bf2f(h0)) | ((unsigned)f2bf(s1-bf2f(h1))<<16),
                                                   (unsigned)f2bf(s2-bf2f(h2)) | ((unsigned)f2bf(s3-bf2f(h3))<<16));
        }
      }
    }
    *(uint2*)&Kl[st*136 + sdk] = kreg;
    if (w==1 && lane<16){
      float c = ebn.x;
      #pragma unroll
      for (int o=1;o<16;o<<=1){ float tv = __shfl_up(c, o, 16); if (lane >= o) c += tv; }
      int q16 = (pb^1)*16;
      clB[q16+lane] = c; blB[q16+lane] = ebn.y; eclB[q16+lane] = __expf(c);
      float c15 = __shfl(c, 15, 16);
      kslB[q16+lane] = __expf(c15 - c);
      if (lane==0) c15B[pb^1] = c15;
    }
    __syncthreads();   // B5
    pb ^= 1;
  }

  if (wsf){
    for (int i = t; i < 64*128; i += 512){
      int dvl = i >> 7, dk = i & 127;
      size_t row = ((size_t)(b*NV_+nv)*128 + half*64 + dvl)*256;
      Sfin[row + dk]       = S0h[dvl*136 + dk];
      Sfin[row + 128 + dk] = S0l[dvl*136 + dk];
    }
  }
}

// ---------------- correction: core[tokens T0TOK..SEQ) += oaug @ Sfin^T (per head) ----------------
__global__ __launch_bounds__(256) void corr_gemm(const ushort_t* __restrict__ oaug, const ushort_t* __restrict__ Sfin,
                                                 float* __restrict__ core){
  __shared__ ushort_t As[128][32];
  __shared__ ushort_t Bs[128][32];
  const int head = blockIdx.y;
  const int m0 = blockIdx.x * 128;
  const int b = head >> 5, nv = head & 31;
  const int t = threadIdx.x, lane = t & 63, w = t >> 6;
  const int wm = w >> 1, wn = w & 1;
  const int srow = lane >> 2, scol = (lane & 3) * 8;
  const ushort_t* Abase = oaug + (size_t)head*HTOK2*128;
  const ushort_t* Bbase = Sfin + (size_t)head*128*256;
  ushort_t* lA0 = &As[     w*16][0];
  ushort_t* lA1 = &As[64 + w*16][0];
  ushort_t* lB0 = &Bs[     w*16][0];
  ushort_t* lB1 = &Bs[64 + w*16][0];
  f32x4 acc[4][4];
  #pragma unroll
  for (int i=0;i<4;i++)
    #pragma unroll
    for (int j=0;j<4;j++) acc[i][j] = (f32x4){0.f,0.f,0.f,0.f};
  const int lr = lane & 15, lk = (lane >> 4) * 8;
  for (int k0 = 0; k0 < 256; k0 += 32){
    const int ka = k0 & 127;
    int ra0 = m0 +      w*16 + srow; if (ra0 >= HTOK2) ra0 = HTOK2 - 1;
    int ra1 = m0 + 64 + w*16 + srow; if (ra1 >= HTOK2) ra1 = HTOK2 - 1;
    __builtin_amdgcn_global_load_lds((const __attribute__((address_space(1))) void*)(Abase + (size_t)ra0*128 + ka + scol),
                                     (__attribute__((address_space(3))) void*)lA0, 16, 0, 0);
    __builtin_amdgcn_global_load_lds((const __attribute__((address_space(1))) void*)(Abase + (size_t)ra1*128 + ka + scol),
                                     (__attribute__((address_space(3))) void*)lA1, 16, 0, 0);
    __builtin_amdgcn_global_load_lds((const __attribute__((address_space(1))) void*)(Bbase + (size_t)(     w*16 + srow)*256 + k0 + scol),
                                     (__attribute__((address_space(3))) void*)lB0, 16, 0, 0);
    __builtin_amdgcn_global_load_lds((const __attribute__((address_space(1))) void*)(Bbase + (size_t)(64 + w*16 + srow)*256 + k0 + scol),
                                     (__attribute__((address_space(3))) void*)lB1, 16, 0, 0);
    __syncthreads();
    bf16x8 af[4], bfv[4];
    #pragma unroll
    for (int i=0;i<4;i++) af[i]  = *(const bf16x8*)&As[wm*64 + i*16 + lr][lk];
    #pragma unroll
    for (int j=0;j<4;j++) bfv[j] = *(const bf16x8*)&Bs[wn*64 + j*16 + lr][lk];
    #pragma unroll
    for (int i=0;i<4;i++)
      #pragma unroll
      for (int j=0;j<4;j++)
        acc[i][j] = __builtin_amdgcn_mfma_f32_16x16x32_bf16(af[i], bfv[j], acc[i][j], 0, 0, 0);
    __syncthreads();
  }
  const int lg = lane >> 4;
  #pragma unroll
  for (int i=0;i<4;i++)
    #pragma unroll
    for (int j=0;j<4;j++)
      #pragma unroll
      for (int r=0;r<4;r++){
        int m = m0 + wm*64 + i*16 + lg*4 + r;
        int n = wn*64 + j*16 + lr;
        if (m < HTOK2){
          float* p = &core[(((size_t)b*SEQ + T0TOK + m)*NV_ + nv)*(size_t)DV_ + n];
          *p += acc[i][j][r];
        }
      }
}

// ---------------- gated RMSNorm -> bf16 ----------------
__global__ __launch_bounds__(128) void gatenorm_kernel(const float* __restrict__ outc, const ushort_t* __restrict__ qkvz,
                                                       const float* __restrict__ norm_w, ushort_t* __restrict__ gated){
  __shared__ float red[2];
  const int blk = blockIdx.x;
  const int nv = blk & 31;
  const size_t bt = (size_t)(blk >> 5);
  const int dv = threadIdx.x;
  float xv = outc[(bt*NV_ + nv)*(size_t)DV_ + dv];
  float ss = xv*xv;
  #pragma unroll
  for (int o=1;o<64;o<<=1) ss += __shfl_xor(ss, o);
  if ((threadIdx.x & 63)==0) red[threadIdx.x>>6] = ss;
  __syncthreads();
  float tot = red[0]+red[1];
  float xn = xv * rsqrtf(tot*(1.f/128.f) + 1e-6f) * norm_w[dv];
  int nk = nv>>1, r = nv&1;
  float z = bf2f(qkvz[bt*NQKVZ + nk*768 + 512 + r*128 + dv]);
  gated[bt*(size_t)4096 + nv*128 + dv] = f2bf(siluf_(z)*xn);
}

extern "C" void kernel_launch(void* const* d_in, const int* in_sizes, int n_in,
                              void* d_out, int out_size, void* d_ws, size_t ws_size,
                              hipStream_t stream){
  (void)in_sizes; (void)n_in; (void)out_size;
  const float* x      = (const float*)d_in[0];
  const float* W_qkvz = (const float*)d_in[1];
  const float* W_ba   = (const float*)d_in[2];
  const float* conv_w = (const float*)d_in[3];
  const float* dt_bias= (const float*)d_in[4];
  const float* A_log  = (const float*)d_in[5];
  const float* norm_w = (const float*)d_in[6];
  const float* W_out  = (const float*)d_in[7];
  float* outp = (float*)d_out;

  char* w = (char*)d_ws;
  const size_t R0 = 0;
  const size_t R1 = 100663296;
  const size_t R2 = R1 + 67108864;
  const size_t R3 = R2 + 67108864;
  const size_t R4 = R3 + 2097152;
  const size_t NEED_SP = R4 + 16777216 + 4194304;
  ushort_t* qkvz_bf = (ushort_t*)(w + R0);
  ushort_t* xb      = (ushort_t*)(w + R1);
  ushort_t* wqt     = (ushort_t*)(w + R1 + 16777216);
  ushort_t* qkv_bf  = (ushort_t*)(w + R1);
  ushort_t* gated   = (ushort_t*)(w + R1);
  float*    core    = (float*)   (w + R2);
  ushort_t* wot     = (ushort_t*)(w + R2);
  float*    ba      = (float*)   (w + R3);
  float2*   egb     = (float2*)  (w + R3 + 1048576);
  ushort_t* oaug    = (ushort_t*)(w + R4);
  ushort_t* Sfin    = (ushort_t*)(w + R4 + 16777216);

  hipError_t e1 = hipFuncSetAttribute((const void*)gemm_big<1>, hipFuncAttributeMaxDynamicSharedMemorySize, 131072);
  hipError_t e2 = hipFuncSetAttribute((const void*)gemm_big2<0>, hipFuncAttributeMaxDynamicSharedMemorySize, 98304);
  hipError_t e3 = hipFuncSetAttribute((const void*)recurrence_chunked, hipFuncAttributeMaxDynamicSharedMemorySize, RLDSZ);
  (void)e1; (void)e2;
  const bool seqpar = (ws_size >= NEED_SP) && (e3 == hipSuccess);

  cast_x_kernel<<<(MTOT*HID/4 + 255)/256, 256, 0, stream>>>(x, xb, MTOT*HID/4);
  transpose_cast<<<dim3(NQKVZ/64, HID/64), 256, 0, stream>>>(W_qkvz, wqt, HID, NQKVZ);
  gemm_big<1><<<dim3(NQKVZ/256, MTOT/256), 512, 131072, stream>>>(xb, wqt, (void*)qkvz_bf, MTOT, NQKVZ, HID);
  gemm_ba<<<MTOT/4, 256, 0, stream>>>(x, W_ba, ba);
  gbeta_kernel<<<(MTOT*NV_+255)/256, 256, 0, stream>>>(ba, A_log, dt_bias, egb);
  conv_norm_kernel<<<(MTOT/CT)*16, 256, 0, stream>>>(qkvz_bf, conv_w, qkv_bf);
  if (seqpar){
    recurrence_chunked<<<256, 512, RLDSZ, stream>>>(qkv_bf, egb, core, oaug, Sfin, 1);
    corr_gemm<<<dim3((HTOK2 + 127)/128, 64), 256, 0, stream>>>(oaug, Sfin, core);
  } else {
    recurrence_chunked<<<128, 512, RLDSZ, stream>>>(qkv_bf, egb, core, oaug, Sfin, 0);
  }
  gatenorm_kernel<<<MTOT*NV_, 128, 0, stream>>>(core, qkvz_bf, norm_w, gated);
  transpose_cast<<<dim3(2048/64, 4096/64), 256, 0, stream>>>(W_out, wot, 4096, 2048);
  gemm_big2<0><<<dim3(2048/128, MTOT/256), 512, 98304, stream>>>(gated, wot, (void*)outp, MTOT, 2048, 4096);
}